// Round 1
// baseline (3338.366 us; speedup 1.0000x reference)
//
#include <hip/hip_runtime.h>
#include <cstddef>

#define N_SRC 100000
#define N_DST 100000
#define NE    1000000
#define D     128
#define R     3
#define NEG   0.2f

__device__ __forceinline__ float eluf(float x) {
    return x > 0.f ? x : expm1f(x);
}

// v[r][k] = sum_c W[r][k][c] * attn_r[r][c]   (tiny)
__global__ void compute_v(const float* __restrict__ fcW, const float* __restrict__ attn_r,
                          float* __restrict__ v) {
    int r = blockIdx.x;
    int i = threadIdx.x; // 0..127
    const float* Wrow = fcW + ((size_t)r * D + i) * D;
    const float* ar = attn_r + r * D;
    float s = 0.f;
    #pragma unroll 4
    for (int j = 0; j < D; j++) s += Wrow[j] * ar[j];
    v[r * D + i] = s;
}

// er[r][n] = dst_feat[n] . v[r]   (one wave per row, all 3 relations)
__global__ __launch_bounds__(256) void compute_er(const float* __restrict__ dst_feat,
                                                  const float* __restrict__ v,
                                                  float* __restrict__ er) {
    int gw = (blockIdx.x * blockDim.x + threadIdx.x) >> 6;
    int lane = threadIdx.x & 63;
    if (gw >= N_DST) return;
    float2 x = ((const float2*)(dst_feat + (size_t)gw * D))[lane];
    #pragma unroll
    for (int r = 0; r < R; r++) {
        float2 vv = ((const float2*)(v + r * D))[lane];
        float s = x.x * vv.x + x.y * vv.y;
        #pragma unroll
        for (int off = 32; off; off >>= 1) s += __shfl_xor(s, off);
        if (lane == 0) er[(size_t)r * N_DST + gw] = s;
    }
}

// el[n] = h_src[n] . attn_l_r   (one wave per row)
__global__ __launch_bounds__(256) void compute_el(const float* __restrict__ hsrc,
                                                  const float* __restrict__ al,
                                                  float* __restrict__ el) {
    int gw = (blockIdx.x * blockDim.x + threadIdx.x) >> 6;
    int lane = threadIdx.x & 63;
    if (gw >= N_SRC) return;
    float2 x = ((const float2*)(hsrc + (size_t)gw * D))[lane];
    float2 a = ((const float2*)al)[lane];
    float s = x.x * a.x + x.y * a.y;
    #pragma unroll
    for (int off = 32; off; off >>= 1) s += __shfl_xor(s, off);
    if (lane == 0) el[gw] = s;
}

// H[M x 128] = X[M x 128] @ W[128 x 128], fp32, 32-row tile per block
__global__ __launch_bounds__(256) void gemm_xw(const float* __restrict__ X,
                                               const float* __restrict__ W,
                                               float* __restrict__ H) {
    __shared__ float Ws[D * D];     // 64 KB
    __shared__ float Xs[32 * D];    // 16 KB
    int tid = threadIdx.x;
    const float4* W4 = (const float4*)W;
    float4* Ws4 = (float4*)Ws;
    #pragma unroll
    for (int t = 0; t < 16; t++) Ws4[tid + 256 * t] = W4[tid + 256 * t];
    size_t row0 = (size_t)blockIdx.x * 32;
    const float4* X4 = (const float4*)(X + row0 * D);
    float4* Xs4 = (float4*)Xs;
    #pragma unroll
    for (int t = 0; t < 4; t++) Xs4[tid + 256 * t] = X4[tid + 256 * t];
    __syncthreads();

    int tx = tid & 31, ty = tid >> 5;
    int c0 = 2 * tx, c2 = 64 + 2 * tx;
    float acc[4][4] = {};
    #pragma unroll 4
    for (int k4 = 0; k4 < 32; k4++) {
        float4 av[4];
        #pragma unroll
        for (int rr = 0; rr < 4; rr++)
            av[rr] = *(const float4*)&Xs[(ty * 4 + rr) * D + k4 * 4];
        #pragma unroll
        for (int j = 0; j < 4; j++) {
            int k = k4 * 4 + j;
            float2 w01 = *(const float2*)&Ws[k * D + c0];
            float2 w23 = *(const float2*)&Ws[k * D + c2];
            #pragma unroll
            for (int rr = 0; rr < 4; rr++) {
                float a = ((const float*)&av[rr])[j];
                acc[rr][0] = fmaf(a, w01.x, acc[rr][0]);
                acc[rr][1] = fmaf(a, w01.y, acc[rr][1]);
                acc[rr][2] = fmaf(a, w23.x, acc[rr][2]);
                acc[rr][3] = fmaf(a, w23.y, acc[rr][3]);
            }
        }
    }
    #pragma unroll
    for (int rr = 0; rr < 4; rr++) {
        size_t row = row0 + ty * 4 + rr;
        *(float2*)&H[row * D + c0] = make_float2(acc[rr][0], acc[rr][1]);
        *(float2*)&H[row * D + c2] = make_float2(acc[rr][2], acc[rr][3]);
    }
}

// per-edge: ex = exp(leaky_relu(el[src]+er[dst])); denom[dst] += ex
__global__ void edge_logits(const float* __restrict__ el, const float* __restrict__ er,
                            const int* __restrict__ es, const int* __restrict__ ed,
                            float* __restrict__ ex, float* __restrict__ denom) {
    int i = blockIdx.x * blockDim.x + threadIdx.x;
    if (i >= NE) return;
    float e = el[es[i]] + er[ed[i]];
    e = e > 0.f ? e : NEG * e;
    float x = expf(e);
    ex[i] = x;
    atomicAdd(&denom[ed[i]], x);
}

// per-edge scatter: rst[dst] += (ex/denom[dst]) * h_src[src]   (1 wave / edge)
__global__ __launch_bounds__(256) void edge_scatter(const float* __restrict__ hsrc,
                                                    const float* __restrict__ ex,
                                                    const float* __restrict__ denom,
                                                    const int* __restrict__ es,
                                                    const int* __restrict__ ed,
                                                    float* __restrict__ rst) {
    int gw = (blockIdx.x * blockDim.x + threadIdx.x) >> 6;
    int lane = threadIdx.x & 63;
    int nw = (gridDim.x * blockDim.x) >> 6;
    for (int i = gw; i < NE; i += nw) {
        int s = es[i], d = ed[i];
        float alpha = ex[i] / denom[d];
        float2 h = ((const float2*)(hsrc + (size_t)s * D))[lane];
        float* out = rst + (size_t)d * D + 2 * lane;
        atomicAdd(out, alpha * h.x);
        atomicAdd(out + 1, alpha * h.y);
    }
}

// partial sums of s[n,r] = tanh(elu(rst+bias) @ W1 + b1) . w2  into ssum[r]
__global__ __launch_bounds__(256) void semantic_partial(const float* __restrict__ rst,
                                                        const float* __restrict__ bias,
                                                        const float* __restrict__ W1,
                                                        const float* __restrict__ b1,
                                                        const float* __restrict__ w2,
                                                        float* __restrict__ ssum) {
    __shared__ float Ws[D * D];
    __shared__ float Xs[32 * D];
    __shared__ float red[4];
    int tid = threadIdx.x;
    const float4* W4 = (const float4*)W1;
    float4* Ws4 = (float4*)Ws;
    #pragma unroll
    for (int t = 0; t < 16; t++) Ws4[tid + 256 * t] = W4[tid + 256 * t];
    int r = blockIdx.x / (N_DST / 32);
    size_t row0 = (size_t)blockIdx.x * 32;
    const float4* biasr4 = (const float4*)(bias + r * D);
    const float4* X4 = (const float4*)(rst + row0 * D);
    float4* Xs4 = (float4*)Xs;
    #pragma unroll
    for (int t = 0; t < 4; t++) {
        int g = tid + 256 * t;
        float4 xv = X4[g];
        float4 bv = biasr4[g & 31];
        float4 zv;
        zv.x = eluf(xv.x + bv.x);
        zv.y = eluf(xv.y + bv.y);
        zv.z = eluf(xv.z + bv.z);
        zv.w = eluf(xv.w + bv.w);
        Xs4[g] = zv;
    }
    __syncthreads();

    int tx = tid & 31, ty = tid >> 5;
    int c0 = 2 * tx, c2 = 64 + 2 * tx;
    float acc[4][4] = {};
    #pragma unroll 4
    for (int k4 = 0; k4 < 32; k4++) {
        float4 av[4];
        #pragma unroll
        for (int rr = 0; rr < 4; rr++)
            av[rr] = *(const float4*)&Xs[(ty * 4 + rr) * D + k4 * 4];
        #pragma unroll
        for (int j = 0; j < 4; j++) {
            int k = k4 * 4 + j;
            float2 w01 = *(const float2*)&Ws[k * D + c0];
            float2 w23 = *(const float2*)&Ws[k * D + c2];
            #pragma unroll
            for (int rr = 0; rr < 4; rr++) {
                float a = ((const float*)&av[rr])[j];
                acc[rr][0] = fmaf(a, w01.x, acc[rr][0]);
                acc[rr][1] = fmaf(a, w01.y, acc[rr][1]);
                acc[rr][2] = fmaf(a, w23.x, acc[rr][2]);
                acc[rr][3] = fmaf(a, w23.y, acc[rr][3]);
            }
        }
    }
    float b10 = b1[c0], b11 = b1[c0 + 1], b12 = b1[c2], b13 = b1[c2 + 1];
    float w20 = w2[c0], w21 = w2[c0 + 1], w22 = w2[c2], w23v = w2[c2 + 1];
    float part = 0.f;
    #pragma unroll
    for (int rr = 0; rr < 4; rr++) {
        part += tanhf(acc[rr][0] + b10) * w20;
        part += tanhf(acc[rr][1] + b11) * w21;
        part += tanhf(acc[rr][2] + b12) * w22;
        part += tanhf(acc[rr][3] + b13) * w23v;
    }
    #pragma unroll
    for (int off = 32; off; off >>= 1) part += __shfl_xor(part, off);
    int lane = tid & 63, wid = tid >> 6;
    if (lane == 0) red[wid] = part;
    __syncthreads();
    if (tid == 0) atomicAdd(&ssum[r], red[0] + red[1] + red[2] + red[3]);
}

__global__ void finalize_a(const float* __restrict__ ssum, float* __restrict__ a_ws,
                           float* __restrict__ out_tail) {
    if (threadIdx.x == 0) {
        float w0 = ssum[0] / (float)N_DST;
        float w1 = ssum[1] / (float)N_DST;
        float w2v = ssum[2] / (float)N_DST;
        float m = fmaxf(w0, fmaxf(w1, w2v));
        float e0 = expf(w0 - m), e1 = expf(w1 - m), e2 = expf(w2v - m);
        float s = e0 + e1 + e2;
        a_ws[0] = e0 / s; a_ws[1] = e1 / s; a_ws[2] = e2 / s;
        out_tail[0] = e0 / s; out_tail[1] = e1 / s; out_tail[2] = e2 / s;
    }
}

// z_out = sum_r a[r] * elu(rst[r] + bias[r])
__global__ __launch_bounds__(256) void combine(const float* __restrict__ rst,
                                               const float* __restrict__ bias,
                                               const float* __restrict__ a,
                                               float* __restrict__ out) {
    int f = blockIdx.x * blockDim.x + threadIdx.x; // float4 index
    if (f >= N_DST * D / 4) return;
    int d4 = f & 31;
    float4 acc = make_float4(0.f, 0.f, 0.f, 0.f);
    #pragma unroll
    for (int r = 0; r < R; r++) {
        float ar = a[r];
        float4 x = ((const float4*)rst)[(size_t)r * (N_DST * D / 4) + f];
        float4 b = ((const float4*)(bias + r * D))[d4];
        acc.x += ar * eluf(x.x + b.x);
        acc.y += ar * eluf(x.y + b.y);
        acc.z += ar * eluf(x.z + b.z);
        acc.w += ar * eluf(x.w + b.w);
    }
    ((float4*)out)[f] = acc;
}

extern "C" void kernel_launch(void* const* d_in, const int* in_sizes, int n_in,
                              void* d_out, int out_size, void* d_ws, size_t ws_size,
                              hipStream_t stream) {
    const float* dst_feat = (const float*)d_in[0];
    const float* src_feat = (const float*)d_in[1];
    const float* fcW      = (const float*)d_in[2];
    const float* attn_l   = (const float*)d_in[3];
    const float* attn_r   = (const float*)d_in[4];
    const float* gat_bias = (const float*)d_in[5];
    const float* sem_W1   = (const float*)d_in[6];
    const float* sem_b1   = (const float*)d_in[7];
    const float* sem_w2   = (const float*)d_in[8];
    const int* edge_src   = (const int*)d_in[9];
    const int* edge_dst   = (const int*)d_in[10];
    float* out = (float*)d_out;

    float* rst   = (float*)d_ws;                       // R*N_DST*D
    float* hsrc  = rst + (size_t)R * N_DST * D;        // N_SRC*D
    float* ex    = hsrc + (size_t)N_SRC * D;           // NE
    float* el    = ex + NE;                            // N_SRC
    float* er    = el + N_SRC;                         // R*N_DST
    float* denom = er + (size_t)R * N_DST;             // N_DST
    float* v     = denom + N_DST;                      // R*D
    float* ssum  = v + R * D;                          // R
    float* a     = ssum + R;                           // R

    hipMemsetAsync(rst, 0, (size_t)R * N_DST * D * sizeof(float), stream);
    hipMemsetAsync(ssum, 0, R * sizeof(float), stream);

    compute_v<<<R, D, 0, stream>>>(fcW, attn_r, v);
    compute_er<<<N_DST / 4, 256, 0, stream>>>(dst_feat, v, er);

    for (int r = 0; r < R; r++) {
        gemm_xw<<<N_SRC / 32, 256, 0, stream>>>(src_feat + (size_t)r * N_SRC * D,
                                                fcW + (size_t)r * D * D, hsrc);
        compute_el<<<N_SRC / 4, 256, 0, stream>>>(hsrc, attn_l + r * D, el);
        hipMemsetAsync(denom, 0, N_DST * sizeof(float), stream);
        edge_logits<<<(NE + 255) / 256, 256, 0, stream>>>(el, er + (size_t)r * N_DST,
                                                          edge_src + (size_t)r * NE,
                                                          edge_dst + (size_t)r * NE,
                                                          ex, denom);
        edge_scatter<<<8192, 256, 0, stream>>>(hsrc, ex, denom,
                                               edge_src + (size_t)r * NE,
                                               edge_dst + (size_t)r * NE,
                                               rst + (size_t)r * N_DST * D);
    }

    semantic_partial<<<R * N_DST / 32, 256, 0, stream>>>(rst, gat_bias, sem_W1,
                                                         sem_b1, sem_w2, ssum);
    finalize_a<<<1, 64, 0, stream>>>(ssum, a, out + (size_t)N_DST * D);
    combine<<<N_DST * D / 4 / 256, 256, 0, stream>>>(rst, gat_bias, a, out);
}

// Round 2
// 1241.799 us; speedup vs baseline: 2.6883x; 2.6883x over previous
//
#include <hip/hip_runtime.h>
#include <cstddef>

#define N_SRC 100000
#define N_DST 100000
#define NE    1000000
#define D     128
#define R     3
#define NEG   0.2f
#define NB    391   // ceil(N_DST/256)

__device__ __forceinline__ float eluf(float x) {
    return x > 0.f ? x : expm1f(x);
}

// v[r][k] = sum_c W[r][k][c] * attn_r[r][c]   (tiny)
__global__ void compute_v(const float* __restrict__ fcW, const float* __restrict__ attn_r,
                          float* __restrict__ v) {
    int r = blockIdx.x;
    int i = threadIdx.x; // 0..127
    const float* Wrow = fcW + ((size_t)r * D + i) * D;
    const float* ar = attn_r + r * D;
    float s = 0.f;
    #pragma unroll 4
    for (int j = 0; j < D; j++) s += Wrow[j] * ar[j];
    v[r * D + i] = s;
}

// er[n] = dst_feat[n] . vr   (one wave per row, single relation)
__global__ __launch_bounds__(256) void compute_er(const float* __restrict__ dst_feat,
                                                  const float* __restrict__ vr,
                                                  float* __restrict__ er) {
    int gw = (blockIdx.x * blockDim.x + threadIdx.x) >> 6;
    int lane = threadIdx.x & 63;
    if (gw >= N_DST) return;
    float2 x = ((const float2*)(dst_feat + (size_t)gw * D))[lane];
    float2 vv = ((const float2*)vr)[lane];
    float s = x.x * vv.x + x.y * vv.y;
    #pragma unroll
    for (int off = 32; off; off >>= 1) s += __shfl_xor(s, off);
    if (lane == 0) er[gw] = s;
}

// el[n] = h_src[n] . attn_l_r   (one wave per row)
__global__ __launch_bounds__(256) void compute_el(const float* __restrict__ hsrc,
                                                  const float* __restrict__ al,
                                                  float* __restrict__ el) {
    int gw = (blockIdx.x * blockDim.x + threadIdx.x) >> 6;
    int lane = threadIdx.x & 63;
    if (gw >= N_SRC) return;
    float2 x = ((const float2*)(hsrc + (size_t)gw * D))[lane];
    float2 a = ((const float2*)al)[lane];
    float s = x.x * a.x + x.y * a.y;
    #pragma unroll
    for (int off = 32; off; off >>= 1) s += __shfl_xor(s, off);
    if (lane == 0) el[gw] = s;
}

// H[M x 128] = X[M x 128] @ W[128 x 128], fp32, 32-row tile per block
__global__ __launch_bounds__(256) void gemm_xw(const float* __restrict__ X,
                                               const float* __restrict__ W,
                                               float* __restrict__ H) {
    __shared__ float Ws[D * D];     // 64 KB
    __shared__ float Xs[32 * D];    // 16 KB
    int tid = threadIdx.x;
    const float4* W4 = (const float4*)W;
    float4* Ws4 = (float4*)Ws;
    #pragma unroll
    for (int t = 0; t < 16; t++) Ws4[tid + 256 * t] = W4[tid + 256 * t];
    size_t row0 = (size_t)blockIdx.x * 32;
    const float4* X4 = (const float4*)(X + row0 * D);
    float4* Xs4 = (float4*)Xs;
    #pragma unroll
    for (int t = 0; t < 4; t++) Xs4[tid + 256 * t] = X4[tid + 256 * t];
    __syncthreads();

    int tx = tid & 31, ty = tid >> 5;
    int c0 = 2 * tx, c2 = 64 + 2 * tx;
    float acc[4][4] = {};
    #pragma unroll 4
    for (int k4 = 0; k4 < 32; k4++) {
        float4 av[4];
        #pragma unroll
        for (int rr = 0; rr < 4; rr++)
            av[rr] = *(const float4*)&Xs[(ty * 4 + rr) * D + k4 * 4];
        #pragma unroll
        for (int j = 0; j < 4; j++) {
            int k = k4 * 4 + j;
            float2 w01 = *(const float2*)&Ws[k * D + c0];
            float2 w23 = *(const float2*)&Ws[k * D + c2];
            #pragma unroll
            for (int rr = 0; rr < 4; rr++) {
                float a = ((const float*)&av[rr])[j];
                acc[rr][0] = fmaf(a, w01.x, acc[rr][0]);
                acc[rr][1] = fmaf(a, w01.y, acc[rr][1]);
                acc[rr][2] = fmaf(a, w23.x, acc[rr][2]);
                acc[rr][3] = fmaf(a, w23.y, acc[rr][3]);
            }
        }
    }
    #pragma unroll
    for (int rr = 0; rr < 4; rr++) {
        size_t row = row0 + ty * 4 + rr;
        *(float2*)&H[row * D + c0] = make_float2(acc[rr][0], acc[rr][1]);
        *(float2*)&H[row * D + c2] = make_float2(acc[rr][2], acc[rr][3]);
    }
}

// ---------- CSR build ----------

__global__ void count_edges(const int* __restrict__ ed, int* __restrict__ cnt) {
    int i = blockIdx.x * blockDim.x + threadIdx.x;
    if (i < NE) atomicAdd(&cnt[ed[i]], 1);
}

// in-place: counts -> per-block exclusive prefix, block totals to bsum
__global__ void scan_blocks(int* __restrict__ rowptr, int* __restrict__ bsum) {
    __shared__ int tmp[256];
    int i = blockIdx.x * 256 + threadIdx.x;
    int x = (i < N_DST) ? rowptr[i] : 0;
    tmp[threadIdx.x] = x;
    __syncthreads();
    #pragma unroll
    for (int off = 1; off < 256; off <<= 1) {
        int v = (threadIdx.x >= off) ? tmp[threadIdx.x - off] : 0;
        __syncthreads();
        tmp[threadIdx.x] += v;
        __syncthreads();
    }
    if (i < N_DST) rowptr[i] = tmp[threadIdx.x] - x;  // exclusive
    if (threadIdx.x == 255) bsum[blockIdx.x] = tmp[255];
}

__global__ void scan_bsum(int* __restrict__ bsum) {
    __shared__ int tmp[512];
    int x = (threadIdx.x < NB) ? bsum[threadIdx.x] : 0;
    tmp[threadIdx.x] = x;
    __syncthreads();
    #pragma unroll
    for (int off = 1; off < 512; off <<= 1) {
        int v = (threadIdx.x >= off) ? tmp[threadIdx.x - off] : 0;
        __syncthreads();
        tmp[threadIdx.x] += v;
        __syncthreads();
    }
    if (threadIdx.x < NB) bsum[threadIdx.x] = tmp[threadIdx.x] - x;  // exclusive
}

__global__ void add_offsets(int* __restrict__ rowptr, const int* __restrict__ bsum,
                            int* __restrict__ cursor) {
    int i = blockIdx.x * 256 + threadIdx.x;
    if (i < N_DST) {
        int vv = rowptr[i] + bsum[blockIdx.x];
        rowptr[i] = vv;
        cursor[i] = vv;
    }
    if (i == 0) rowptr[N_DST] = NE;
}

__global__ void place_edges(const int* __restrict__ es, const int* __restrict__ ed,
                            int* __restrict__ cursor, int* __restrict__ csr_src) {
    int i = blockIdx.x * blockDim.x + threadIdx.x;
    if (i >= NE) return;
    int pos = atomicAdd(&cursor[ed[i]], 1);
    csr_src[pos] = es[i];
}

// ---------- per-dst gather + softmax + elu, one wave per dst ----------
__global__ __launch_bounds__(256) void aggregate(const float* __restrict__ hsrc,
                                                 const int* __restrict__ csr_src,
                                                 const int* __restrict__ rowptr,
                                                 const float* __restrict__ el,
                                                 const float* __restrict__ er,
                                                 const float* __restrict__ bias_r,
                                                 float* __restrict__ z_r) {
    int gw = (blockIdx.x * blockDim.x + threadIdx.x) >> 6;
    int lane = threadIdx.x & 63;
    if (gw >= N_DST) return;
    int beg = rowptr[gw], end = rowptr[gw + 1];
    float erd = er[gw];
    float2 acc = make_float2(0.f, 0.f);
    float sum = 0.f;
    int i = beg;
    for (; i + 2 <= end; i += 2) {
        int s0 = csr_src[i], s1 = csr_src[i + 1];
        float e0 = el[s0] + erd, e1 = el[s1] + erd;
        e0 = e0 > 0.f ? e0 : NEG * e0;
        e1 = e1 > 0.f ? e1 : NEG * e1;
        float x0 = expf(e0), x1 = expf(e1);
        float2 h0 = ((const float2*)(hsrc + (size_t)s0 * D))[lane];
        float2 h1 = ((const float2*)(hsrc + (size_t)s1 * D))[lane];
        acc.x = fmaf(x0, h0.x, acc.x);
        acc.y = fmaf(x0, h0.y, acc.y);
        acc.x = fmaf(x1, h1.x, acc.x);
        acc.y = fmaf(x1, h1.y, acc.y);
        sum += x0 + x1;
    }
    if (i < end) {
        int s0 = csr_src[i];
        float e0 = el[s0] + erd;
        e0 = e0 > 0.f ? e0 : NEG * e0;
        float x0 = expf(e0);
        float2 h0 = ((const float2*)(hsrc + (size_t)s0 * D))[lane];
        acc.x = fmaf(x0, h0.x, acc.x);
        acc.y = fmaf(x0, h0.y, acc.y);
        sum += x0;
    }
    float inv = sum > 0.f ? 1.f / sum : 0.f;
    float2 b = ((const float2*)bias_r)[lane];
    float2 z;
    z.x = eluf(fmaf(acc.x, inv, b.x));
    z.y = eluf(fmaf(acc.y, inv, b.y));
    ((float2*)(z_r + (size_t)gw * D))[lane] = z;
}

// partial sums of s[n,r] = tanh(z @ W1 + b1) . w2  into ssum[r]
__global__ __launch_bounds__(256) void semantic_partial(const float* __restrict__ z,
                                                        const float* __restrict__ W1,
                                                        const float* __restrict__ b1,
                                                        const float* __restrict__ w2,
                                                        float* __restrict__ ssum) {
    __shared__ float Ws[D * D];
    __shared__ float Xs[32 * D];
    __shared__ float red[4];
    int tid = threadIdx.x;
    const float4* W4 = (const float4*)W1;
    float4* Ws4 = (float4*)Ws;
    #pragma unroll
    for (int t = 0; t < 16; t++) Ws4[tid + 256 * t] = W4[tid + 256 * t];
    int r = blockIdx.x / (N_DST / 32);
    size_t row0 = (size_t)blockIdx.x * 32;
    const float4* X4 = (const float4*)(z + row0 * D);
    float4* Xs4 = (float4*)Xs;
    #pragma unroll
    for (int t = 0; t < 4; t++) Xs4[tid + 256 * t] = X4[tid + 256 * t];
    __syncthreads();

    int tx = tid & 31, ty = tid >> 5;
    int c0 = 2 * tx, c2 = 64 + 2 * tx;
    float acc[4][4] = {};
    #pragma unroll 4
    for (int k4 = 0; k4 < 32; k4++) {
        float4 av[4];
        #pragma unroll
        for (int rr = 0; rr < 4; rr++)
            av[rr] = *(const float4*)&Xs[(ty * 4 + rr) * D + k4 * 4];
        #pragma unroll
        for (int j = 0; j < 4; j++) {
            int k = k4 * 4 + j;
            float2 w01 = *(const float2*)&Ws[k * D + c0];
            float2 w23 = *(const float2*)&Ws[k * D + c2];
            #pragma unroll
            for (int rr = 0; rr < 4; rr++) {
                float a = ((const float*)&av[rr])[j];
                acc[rr][0] = fmaf(a, w01.x, acc[rr][0]);
                acc[rr][1] = fmaf(a, w01.y, acc[rr][1]);
                acc[rr][2] = fmaf(a, w23.x, acc[rr][2]);
                acc[rr][3] = fmaf(a, w23.y, acc[rr][3]);
            }
        }
    }
    float b10 = b1[c0], b11 = b1[c0 + 1], b12 = b1[c2], b13 = b1[c2 + 1];
    float w20 = w2[c0], w21 = w2[c0 + 1], w22 = w2[c2], w23v = w2[c2 + 1];
    float part = 0.f;
    #pragma unroll
    for (int rr = 0; rr < 4; rr++) {
        part += tanhf(acc[rr][0] + b10) * w20;
        part += tanhf(acc[rr][1] + b11) * w21;
        part += tanhf(acc[rr][2] + b12) * w22;
        part += tanhf(acc[rr][3] + b13) * w23v;
    }
    #pragma unroll
    for (int off = 32; off; off >>= 1) part += __shfl_xor(part, off);
    int lane = tid & 63, wid = tid >> 6;
    if (lane == 0) red[wid] = part;
    __syncthreads();
    if (tid == 0) atomicAdd(&ssum[r], red[0] + red[1] + red[2] + red[3]);
}

__global__ void finalize_a(const float* __restrict__ ssum, float* __restrict__ a_ws,
                           float* __restrict__ out_tail) {
    if (threadIdx.x == 0) {
        float w0 = ssum[0] / (float)N_DST;
        float w1 = ssum[1] / (float)N_DST;
        float w2v = ssum[2] / (float)N_DST;
        float m = fmaxf(w0, fmaxf(w1, w2v));
        float e0 = expf(w0 - m), e1 = expf(w1 - m), e2 = expf(w2v - m);
        float s = e0 + e1 + e2;
        a_ws[0] = e0 / s; a_ws[1] = e1 / s; a_ws[2] = e2 / s;
        out_tail[0] = e0 / s; out_tail[1] = e1 / s; out_tail[2] = e2 / s;
    }
}

// z_out = sum_r a[r] * z[r]
__global__ __launch_bounds__(256) void combine(const float* __restrict__ z,
                                               const float* __restrict__ a,
                                               float* __restrict__ out) {
    int f = blockIdx.x * blockDim.x + threadIdx.x; // float4 index
    if (f >= N_DST * D / 4) return;
    float4 acc = make_float4(0.f, 0.f, 0.f, 0.f);
    #pragma unroll
    for (int r = 0; r < R; r++) {
        float ar = a[r];
        float4 x = ((const float4*)z)[(size_t)r * (N_DST * D / 4) + f];
        acc.x += ar * x.x;
        acc.y += ar * x.y;
        acc.z += ar * x.z;
        acc.w += ar * x.w;
    }
    ((float4*)out)[f] = acc;
}

extern "C" void kernel_launch(void* const* d_in, const int* in_sizes, int n_in,
                              void* d_out, int out_size, void* d_ws, size_t ws_size,
                              hipStream_t stream) {
    const float* dst_feat = (const float*)d_in[0];
    const float* src_feat = (const float*)d_in[1];
    const float* fcW      = (const float*)d_in[2];
    const float* attn_l   = (const float*)d_in[3];
    const float* attn_r   = (const float*)d_in[4];
    const float* gat_bias = (const float*)d_in[5];
    const float* sem_W1   = (const float*)d_in[6];
    const float* sem_b1   = (const float*)d_in[7];
    const float* sem_w2   = (const float*)d_in[8];
    const int* edge_src   = (const int*)d_in[9];
    const int* edge_dst   = (const int*)d_in[10];
    float* out = (float*)d_out;

    float* z    = (float*)d_ws;                    // R*N_DST*D
    float* hsrc = z + (size_t)R * N_DST * D;       // N_SRC*D
    float* el   = hsrc + (size_t)N_SRC * D;        // N_SRC
    float* er   = el + N_SRC;                      // N_DST (per-relation reuse)
    float* v    = er + N_DST;                      // R*D
    float* ssum = v + R * D;                       // R
    float* a    = ssum + R;                        // R
    int* rowptr = (int*)(a + R);                   // N_DST+1
    int* cursor = rowptr + N_DST + 1;              // N_DST
    int* bsum   = cursor + N_DST;                  // 512
    int* csr_src= bsum + 512;                      // NE

    hipMemsetAsync(ssum, 0, R * sizeof(float), stream);
    compute_v<<<R, D, 0, stream>>>(fcW, attn_r, v);

    for (int r = 0; r < R; r++) {
        const int* es = edge_src + (size_t)r * NE;
        const int* ed = edge_dst + (size_t)r * NE;
        // CSR build (depends only on edges)
        hipMemsetAsync(rowptr, 0, (N_DST + 1) * sizeof(int), stream);
        count_edges<<<(NE + 255) / 256, 256, 0, stream>>>(ed, rowptr);
        scan_blocks<<<NB, 256, 0, stream>>>(rowptr, bsum);
        scan_bsum<<<1, 512, 0, stream>>>(bsum);
        add_offsets<<<NB, 256, 0, stream>>>(rowptr, bsum, cursor);
        place_edges<<<(NE + 255) / 256, 256, 0, stream>>>(es, ed, cursor, csr_src);
        // dense phase
        gemm_xw<<<N_SRC / 32, 256, 0, stream>>>(src_feat + (size_t)r * N_SRC * D,
                                                fcW + (size_t)r * D * D, hsrc);
        compute_el<<<N_SRC / 4, 256, 0, stream>>>(hsrc, attn_l + r * D, el);
        compute_er<<<N_DST / 4, 256, 0, stream>>>(dst_feat, v + r * D, er);
        // gather + softmax + elu -> z
        aggregate<<<N_DST / 4, 256, 0, stream>>>(hsrc, csr_src, rowptr, el, er,
                                                 gat_bias + r * D,
                                                 z + (size_t)r * N_DST * D);
    }

    semantic_partial<<<R * N_DST / 32, 256, 0, stream>>>(z, sem_W1, sem_b1, sem_w2, ssum);
    finalize_a<<<1, 64, 0, stream>>>(ssum, a, out + (size_t)N_DST * D);
    combine<<<N_DST * D / 4 / 256, 256, 0, stream>>>(z, a, out);
}

// Round 3
// 885.443 us; speedup vs baseline: 3.7703x; 1.4025x over previous
//
#include <hip/hip_runtime.h>
#include <cstddef>
#include <cstdint>

#define N_SRC 100000
#define N_DST 100000
#define NE    1000000
#define D     128
#define R     3
#define NEG   0.2f
#define NB    391                         // ceil(N_DST/256)
#define NROWS_SEM (R * N_DST)
#define NBH   ((N_SRC + 127) / 128)       // 782
#define NBS   ((NROWS_SEM + 127) / 128)   // 2344

typedef __attribute__((ext_vector_type(8))) short bf16x8;
typedef __attribute__((ext_vector_type(4))) float f32x4;

__device__ __forceinline__ float b2f(unsigned short u) {
    union { unsigned int i; float f; } v; v.i = ((unsigned int)u) << 16; return v.f;
}
__device__ __forceinline__ unsigned short f2b(float f) {
    union { float f; unsigned int i; } v; v.f = f;
    unsigned int x = v.i;
    return (unsigned short)((x + 0x7fffu + ((x >> 16) & 1u)) >> 16);  // RNE
}
__device__ __forceinline__ float eluf(float x) {
    return x > 0.f ? x : expm1f(x);
}

// v[r][k] = sum_c W[r][k][c] * attn_r[r][c]
__global__ void compute_v(const float* __restrict__ fcW, const float* __restrict__ attn_r,
                          float* __restrict__ v) {
    int r = blockIdx.x;
    int i = threadIdx.x;
    const float* Wrow = fcW + ((size_t)r * D + i) * D;
    const float* ar = attn_r + r * D;
    float s = 0.f;
    #pragma unroll 4
    for (int j = 0; j < D; j++) s += Wrow[j] * ar[j];
    v[r * D + i] = s;
}

// Whi_t/Wlo_t[r][n][k] = split_bf16(W[r][k][n])  (transposed for MFMA B-frags)
__global__ void prep_w(const float* __restrict__ fcW, unsigned short* __restrict__ Wh,
                       unsigned short* __restrict__ Wl) {
    int r = blockIdx.x;
    for (int i = threadIdx.x; i < D * D; i += 256) {
        int n = i >> 7, k = i & 127;
        float x = fcW[(size_t)r * D * D + k * D + n];
        unsigned short hi = f2b(x);
        Wh[(size_t)r * D * D + i] = hi;
        Wl[(size_t)r * D * D + i] = f2b(x - b2f(hi));
    }
}

__global__ void prep_w1(const float* __restrict__ W1, unsigned short* __restrict__ W1t) {
    for (int i = threadIdx.x; i < D * D; i += 256) {
        int n = i >> 7, k = i & 127;
        W1t[i] = f2b(W1[k * D + n]);
    }
}

// er[n] = dst_feat[n] . vr
__global__ __launch_bounds__(256) void compute_er(const float* __restrict__ dst_feat,
                                                  const float* __restrict__ vr,
                                                  float* __restrict__ er) {
    int gw = (blockIdx.x * blockDim.x + threadIdx.x) >> 6;
    int lane = threadIdx.x & 63;
    if (gw >= N_DST) return;
    float2 x = ((const float2*)(dst_feat + (size_t)gw * D))[lane];
    float2 vv = ((const float2*)vr)[lane];
    float s = x.x * vv.x + x.y * vv.y;
    #pragma unroll
    for (int off = 32; off; off >>= 1) s += __shfl_xor(s, off);
    if (lane == 0) er[gw] = s;
}

// ---------- MFMA GEMM: H = X @ W (bf16x3), fused el = H @ attn_l, H stored bf16 ----------
__global__ __launch_bounds__(512) void gemm_h(const float* __restrict__ X,
        const unsigned short* __restrict__ Wh, const unsigned short* __restrict__ Wl,
        const float* __restrict__ al,
        unsigned short* __restrict__ H, float* __restrict__ el) {
    __shared__ short Xh[16384], Xl[16384], Bh[16384], Bl[16384];  // 128 KB
    int tid = threadIdx.x;
    size_t row0 = (size_t)blockIdx.x * 128;
    // stage X (fp32 -> bf16 hi/lo, XOR-swizzled at 16B blocks)
    #pragma unroll
    for (int p = 0; p < 8; p++) {
        int c = p * 512 + tid;
        int m = c >> 5, c4 = c & 31;
        float4 xv = make_float4(0.f, 0.f, 0.f, 0.f);
        if (row0 + m < N_SRC) xv = ((const float4*)(X + (row0 + m) * D))[c4];
        unsigned short h0 = f2b(xv.x), h1 = f2b(xv.y), h2 = f2b(xv.z), h3 = f2b(xv.w);
        unsigned short l0 = f2b(xv.x - b2f(h0)), l1 = f2b(xv.y - b2f(h1));
        unsigned short l2 = f2b(xv.z - b2f(h2)), l3 = f2b(xv.w - b2f(h3));
        int idx = m * 128 + (((c4 >> 1) ^ (m & 7)) << 3) + ((c4 & 1) << 2);
        *(uint2*)&Xh[idx] = make_uint2((unsigned)h0 | ((unsigned)h1 << 16),
                                       (unsigned)h2 | ((unsigned)h3 << 16));
        *(uint2*)&Xl[idx] = make_uint2((unsigned)l0 | ((unsigned)l1 << 16),
                                       (unsigned)l2 | ((unsigned)l3 << 16));
    }
    // stage W (already transposed+split in global)
    #pragma unroll
    for (int p = 0; p < 4; p++) {
        int c = p * 512 + tid;
        int n = c >> 4, cb = c & 15;
        int idx = n * 128 + ((cb ^ (n & 7)) << 3);
        *(uint4*)&Bh[idx] = ((const uint4*)Wh)[c];
        *(uint4*)&Bl[idx] = ((const uint4*)Wl)[c];
    }
    __syncthreads();

    int w = tid >> 6, lane = tid & 63, lr = lane & 15, lg = lane >> 4;
    f32x4 acc[8];
    #pragma unroll
    for (int nt = 0; nt < 8; nt++) acc[nt] = (f32x4){0.f, 0.f, 0.f, 0.f};
    int m = w * 16 + lr;
    #pragma unroll
    for (int kk = 0; kk < 4; kk++) {
        int cb = kk * 4 + lg;
        int ia = m * 128 + ((cb ^ (m & 7)) << 3);
        bf16x8 ah = *(const bf16x8*)&Xh[ia];
        bf16x8 alo = *(const bf16x8*)&Xl[ia];
        #pragma unroll
        for (int nt = 0; nt < 8; nt++) {
            int n = nt * 16 + lr;
            int ib = n * 128 + ((cb ^ (n & 7)) << 3);
            bf16x8 bh = *(const bf16x8*)&Bh[ib];
            bf16x8 bl = *(const bf16x8*)&Bl[ib];
            acc[nt] = __builtin_amdgcn_mfma_f32_16x16x32_bf16(ah, bh, acc[nt], 0, 0, 0);
            acc[nt] = __builtin_amdgcn_mfma_f32_16x16x32_bf16(alo, bh, acc[nt], 0, 0, 0);
            acc[nt] = __builtin_amdgcn_mfma_f32_16x16x32_bf16(ah, bl, acc[nt], 0, 0, 0);
        }
    }
    // epilogue: store H bf16 + fused el row-dot
    float alv[8];
    #pragma unroll
    for (int nt = 0; nt < 8; nt++) alv[nt] = al[nt * 16 + lr];
    #pragma unroll
    for (int reg = 0; reg < 4; reg++) {
        size_t row = row0 + w * 16 + lg * 4 + reg;
        bool ok = row < N_SRC;
        float ep = 0.f;
        #pragma unroll
        for (int nt = 0; nt < 8; nt++) {
            float hv = acc[nt][reg];
            ep = fmaf(hv, alv[nt], ep);
            if (ok) H[row * D + nt * 16 + lr] = f2b(hv);
        }
        ep += __shfl_xor(ep, 1); ep += __shfl_xor(ep, 2);
        ep += __shfl_xor(ep, 4); ep += __shfl_xor(ep, 8);
        if (ok && lr == 0) el[row] = ep;
    }
}

// ---------- MFMA GEMM: per-block partials of sum_n tanh(z@W1+b1).w2, grouped by relation ----------
__global__ __launch_bounds__(512) void gemm_sem(const float* __restrict__ Z,
        const unsigned short* __restrict__ W1t, const float* __restrict__ b1,
        const float* __restrict__ w2, float* __restrict__ psem) {
    __shared__ short Xh[16384], Bh[16384];   // 64 KB
    __shared__ float redw[8][4];
    int tid = threadIdx.x;
    size_t row0 = (size_t)blockIdx.x * 128;
    #pragma unroll
    for (int p = 0; p < 8; p++) {
        int c = p * 512 + tid;
        int m = c >> 5, c4 = c & 31;
        float4 xv = make_float4(0.f, 0.f, 0.f, 0.f);
        if (row0 + m < NROWS_SEM) xv = ((const float4*)(Z + (row0 + m) * D))[c4];
        int idx = m * 128 + (((c4 >> 1) ^ (m & 7)) << 3) + ((c4 & 1) << 2);
        *(uint2*)&Xh[idx] = make_uint2((unsigned)f2b(xv.x) | ((unsigned)f2b(xv.y) << 16),
                                       (unsigned)f2b(xv.z) | ((unsigned)f2b(xv.w) << 16));
    }
    #pragma unroll
    for (int p = 0; p < 4; p++) {
        int c = p * 512 + tid;
        int n = c >> 4, cb = c & 15;
        int idx = n * 128 + ((cb ^ (n & 7)) << 3);
        *(uint4*)&Bh[idx] = ((const uint4*)W1t)[c];
    }
    __syncthreads();

    int w = tid >> 6, lane = tid & 63, lr = lane & 15, lg = lane >> 4;
    f32x4 acc[8];
    #pragma unroll
    for (int nt = 0; nt < 8; nt++) acc[nt] = (f32x4){0.f, 0.f, 0.f, 0.f};
    int m = w * 16 + lr;
    #pragma unroll
    for (int kk = 0; kk < 4; kk++) {
        int cb = kk * 4 + lg;
        int ia = m * 128 + ((cb ^ (m & 7)) << 3);
        bf16x8 ah = *(const bf16x8*)&Xh[ia];
        #pragma unroll
        for (int nt = 0; nt < 8; nt++) {
            int n = nt * 16 + lr;
            int ib = n * 128 + ((cb ^ (n & 7)) << 3);
            bf16x8 bh = *(const bf16x8*)&Bh[ib];
            acc[nt] = __builtin_amdgcn_mfma_f32_16x16x32_bf16(ah, bh, acc[nt], 0, 0, 0);
        }
    }
    float b1v[8], w2v[8];
    #pragma unroll
    for (int nt = 0; nt < 8; nt++) { b1v[nt] = b1[nt * 16 + lr]; w2v[nt] = w2[nt * 16 + lr]; }
    float rs0 = 0.f, rs1 = 0.f, rs2 = 0.f;
    #pragma unroll
    for (int reg = 0; reg < 4; reg++) {
        size_t row = row0 + w * 16 + lg * 4 + reg;
        float sv = 0.f;
        #pragma unroll
        for (int nt = 0; nt < 8; nt++)
            sv += tanhf(acc[nt][reg] + b1v[nt]) * w2v[nt];
        sv += __shfl_xor(sv, 1); sv += __shfl_xor(sv, 2);
        sv += __shfl_xor(sv, 4); sv += __shfl_xor(sv, 8);
        if (lr == 0 && row < NROWS_SEM) {
            int r = (int)(row / N_DST);
            if (r == 0) rs0 += sv; else if (r == 1) rs1 += sv; else rs2 += sv;
        }
    }
    rs0 += __shfl_xor(rs0, 16); rs0 += __shfl_xor(rs0, 32);
    rs1 += __shfl_xor(rs1, 16); rs1 += __shfl_xor(rs1, 32);
    rs2 += __shfl_xor(rs2, 16); rs2 += __shfl_xor(rs2, 32);
    if (lane == 0) { redw[w][0] = rs0; redw[w][1] = rs1; redw[w][2] = rs2; }
    __syncthreads();
    if (tid < 3) {
        float s = 0.f;
        #pragma unroll
        for (int i = 0; i < 8; i++) s += redw[i][tid];
        psem[blockIdx.x * 3 + tid] = s;
    }
}

// ---------- CSR build ----------
__global__ void count_edges(const int* __restrict__ ed, int* __restrict__ cnt) {
    int i = blockIdx.x * blockDim.x + threadIdx.x;
    if (i < NE) atomicAdd(&cnt[ed[i]], 1);
}

__global__ void scan_blocks(int* __restrict__ rowptr, int* __restrict__ bsum) {
    __shared__ int tmp[256];
    int i = blockIdx.x * 256 + threadIdx.x;
    int x = (i < N_DST) ? rowptr[i] : 0;
    tmp[threadIdx.x] = x;
    __syncthreads();
    #pragma unroll
    for (int off = 1; off < 256; off <<= 1) {
        int v = (threadIdx.x >= off) ? tmp[threadIdx.x - off] : 0;
        __syncthreads();
        tmp[threadIdx.x] += v;
        __syncthreads();
    }
    if (i < N_DST) rowptr[i] = tmp[threadIdx.x] - x;
    if (threadIdx.x == 255) bsum[blockIdx.x] = tmp[255];
}

__global__ void scan_bsum(int* __restrict__ bsum) {
    __shared__ int tmp[512];
    int x = (threadIdx.x < NB) ? bsum[threadIdx.x] : 0;
    tmp[threadIdx.x] = x;
    __syncthreads();
    #pragma unroll
    for (int off = 1; off < 512; off <<= 1) {
        int v = (threadIdx.x >= off) ? tmp[threadIdx.x - off] : 0;
        __syncthreads();
        tmp[threadIdx.x] += v;
        __syncthreads();
    }
    if (threadIdx.x < NB) bsum[threadIdx.x] = tmp[threadIdx.x] - x;
}

__global__ void add_offsets(int* __restrict__ rowptr, const int* __restrict__ bsum,
                            int* __restrict__ cursor) {
    int i = blockIdx.x * 256 + threadIdx.x;
    if (i < N_DST) {
        int vv = rowptr[i] + bsum[blockIdx.x];
        rowptr[i] = vv;
        cursor[i] = vv;
    }
    if (i == 0) rowptr[N_DST] = NE;
}

__global__ void place_edges(const int* __restrict__ es, const int* __restrict__ ed,
                            int* __restrict__ cursor, int* __restrict__ csr_src) {
    int i = blockIdx.x * blockDim.x + threadIdx.x;
    if (i >= NE) return;
    int pos = atomicAdd(&cursor[ed[i]], 1);
    csr_src[pos] = es[i];
}

// ---------- per-dst gather + softmax + elu (h in bf16) ----------
__global__ __launch_bounds__(256) void aggregate(const unsigned short* __restrict__ hsrc,
                                                 const int* __restrict__ csr_src,
                                                 const int* __restrict__ rowptr,
                                                 const float* __restrict__ el,
                                                 const float* __restrict__ er,
                                                 const float* __restrict__ bias_r,
                                                 float* __restrict__ z_r) {
    int gw = (blockIdx.x * blockDim.x + threadIdx.x) >> 6;
    int lane = threadIdx.x & 63;
    if (gw >= N_DST) return;
    int beg = rowptr[gw], end = rowptr[gw + 1];
    float erd = er[gw];
    float2 acc = make_float2(0.f, 0.f);
    float sum = 0.f;
    int i = beg;
    for (; i + 2 <= end; i += 2) {
        int s0 = csr_src[i], s1 = csr_src[i + 1];
        float e0 = el[s0] + erd, e1 = el[s1] + erd;
        e0 = e0 > 0.f ? e0 : NEG * e0;
        e1 = e1 > 0.f ? e1 : NEG * e1;
        float x0 = expf(e0), x1 = expf(e1);
        ushort2 u0 = ((const ushort2*)(hsrc + (size_t)s0 * D))[lane];
        ushort2 u1 = ((const ushort2*)(hsrc + (size_t)s1 * D))[lane];
        acc.x = fmaf(x0, b2f(u0.x), acc.x);
        acc.y = fmaf(x0, b2f(u0.y), acc.y);
        acc.x = fmaf(x1, b2f(u1.x), acc.x);
        acc.y = fmaf(x1, b2f(u1.y), acc.y);
        sum += x0 + x1;
    }
    if (i < end) {
        int s0 = csr_src[i];
        float e0 = el[s0] + erd;
        e0 = e0 > 0.f ? e0 : NEG * e0;
        float x0 = expf(e0);
        ushort2 u0 = ((const ushort2*)(hsrc + (size_t)s0 * D))[lane];
        acc.x = fmaf(x0, b2f(u0.x), acc.x);
        acc.y = fmaf(x0, b2f(u0.y), acc.y);
        sum += x0;
    }
    float inv = sum > 0.f ? 1.f / sum : 0.f;
    float2 b = ((const float2*)bias_r)[lane];
    float2 z;
    z.x = eluf(fmaf(acc.x, inv, b.x));
    z.y = eluf(fmaf(acc.y, inv, b.y));
    ((float2*)(z_r + (size_t)gw * D))[lane] = z;
}

__global__ void finalize_a(const float* __restrict__ psem, float* __restrict__ a_ws,
                           float* __restrict__ out_tail) {
    __shared__ float red[4][4];
    float s0 = 0.f, s1 = 0.f, s2 = 0.f;
    for (int b = threadIdx.x; b < NBS; b += 256) {
        s0 += psem[b * 3]; s1 += psem[b * 3 + 1]; s2 += psem[b * 3 + 2];
    }
    #pragma unroll
    for (int off = 32; off; off >>= 1) {
        s0 += __shfl_xor(s0, off); s1 += __shfl_xor(s1, off); s2 += __shfl_xor(s2, off);
    }
    int w = threadIdx.x >> 6;
    if ((threadIdx.x & 63) == 0) { red[w][0] = s0; red[w][1] = s1; red[w][2] = s2; }
    __syncthreads();
    if (threadIdx.x == 0) {
        float w0 = 0.f, w1 = 0.f, w2v = 0.f;
        #pragma unroll
        for (int i = 0; i < 4; i++) { w0 += red[i][0]; w1 += red[i][1]; w2v += red[i][2]; }
        w0 /= (float)N_DST; w1 /= (float)N_DST; w2v /= (float)N_DST;
        float m = fmaxf(w0, fmaxf(w1, w2v));
        float e0 = expf(w0 - m), e1 = expf(w1 - m), e2 = expf(w2v - m);
        float s = e0 + e1 + e2;
        a_ws[0] = e0 / s; a_ws[1] = e1 / s; a_ws[2] = e2 / s;
        out_tail[0] = e0 / s; out_tail[1] = e1 / s; out_tail[2] = e2 / s;
    }
}

__global__ __launch_bounds__(256) void combine(const float* __restrict__ z,
                                               const float* __restrict__ a,
                                               float* __restrict__ out) {
    int f = blockIdx.x * blockDim.x + threadIdx.x;
    if (f >= N_DST * D / 4) return;
    float4 acc = make_float4(0.f, 0.f, 0.f, 0.f);
    #pragma unroll
    for (int r = 0; r < R; r++) {
        float ar = a[r];
        float4 x = ((const float4*)z)[(size_t)r * (N_DST * D / 4) + f];
        acc.x += ar * x.x;
        acc.y += ar * x.y;
        acc.z += ar * x.z;
        acc.w += ar * x.w;
    }
    ((float4*)out)[f] = acc;
}

extern "C" void kernel_launch(void* const* d_in, const int* in_sizes, int n_in,
                              void* d_out, int out_size, void* d_ws, size_t ws_size,
                              hipStream_t stream) {
    const float* dst_feat = (const float*)d_in[0];
    const float* src_feat = (const float*)d_in[1];
    const float* fcW      = (const float*)d_in[2];
    const float* attn_l   = (const float*)d_in[3];
    const float* attn_r   = (const float*)d_in[4];
    const float* gat_bias = (const float*)d_in[5];
    const float* sem_W1   = (const float*)d_in[6];
    const float* sem_b1   = (const float*)d_in[7];
    const float* sem_w2   = (const float*)d_in[8];
    const int* edge_src   = (const int*)d_in[9];
    const int* edge_dst   = (const int*)d_in[10];
    float* out = (float*)d_out;

    char* p = (char*)d_ws;
    auto alloc = [&](size_t bytes) {
        p = (char*)(((uintptr_t)p + 255) & ~(uintptr_t)255);
        char* r = p; p += bytes; return (void*)r;
    };
    float* z      = (float*)alloc((size_t)R * N_DST * D * sizeof(float));
    float* el     = (float*)alloc(N_SRC * sizeof(float));
    float* er     = (float*)alloc(N_DST * sizeof(float));
    float* v      = (float*)alloc(R * D * sizeof(float));
    float* a      = (float*)alloc(R * sizeof(float));
    float* psem   = (float*)alloc((size_t)NBS * 3 * sizeof(float));
    unsigned short* hsrc = (unsigned short*)alloc((size_t)N_SRC * D * sizeof(short));
    unsigned short* Whi  = (unsigned short*)alloc((size_t)R * D * D * sizeof(short));
    unsigned short* Wlo  = (unsigned short*)alloc((size_t)R * D * D * sizeof(short));
    unsigned short* W1t  = (unsigned short*)alloc((size_t)D * D * sizeof(short));
    int* rowptr  = (int*)alloc((N_DST + 1) * sizeof(int));
    int* cursor  = (int*)alloc(N_DST * sizeof(int));
    int* bsum    = (int*)alloc(512 * sizeof(int));
    int* csr_src = (int*)alloc((size_t)NE * sizeof(int));

    prep_w<<<R, 256, 0, stream>>>(fcW, Whi, Wlo);
    prep_w1<<<1, 256, 0, stream>>>(sem_W1, W1t);
    compute_v<<<R, D, 0, stream>>>(fcW, attn_r, v);

    for (int r = 0; r < R; r++) {
        const int* es = edge_src + (size_t)r * NE;
        const int* ed = edge_dst + (size_t)r * NE;
        hipMemsetAsync(rowptr, 0, (N_DST + 1) * sizeof(int), stream);
        count_edges<<<(NE + 255) / 256, 256, 0, stream>>>(ed, rowptr);
        scan_blocks<<<NB, 256, 0, stream>>>(rowptr, bsum);
        scan_bsum<<<1, 512, 0, stream>>>(bsum);
        add_offsets<<<NB, 256, 0, stream>>>(rowptr, bsum, cursor);
        place_edges<<<(NE + 255) / 256, 256, 0, stream>>>(es, ed, cursor, csr_src);

        gemm_h<<<NBH, 512, 0, stream>>>(src_feat + (size_t)r * N_SRC * D,
                                        Whi + (size_t)r * D * D, Wlo + (size_t)r * D * D,
                                        attn_l + r * D, hsrc, el);
        compute_er<<<N_DST / 4, 256, 0, stream>>>(dst_feat, v + r * D, er);
        aggregate<<<N_DST / 4, 256, 0, stream>>>(hsrc, csr_src, rowptr, el, er,
                                                 gat_bias + r * D,
                                                 z + (size_t)r * N_DST * D);
    }

    gemm_sem<<<NBS, 512, 0, stream>>>(z, W1t, sem_b1, sem_w2, psem);
    finalize_a<<<1, 256, 0, stream>>>(psem, a, out + (size_t)N_DST * D);
    combine<<<N_DST * D / 4 / 256, 256, 0, stream>>>(z, a, out);
}

// Round 4
// 829.402 us; speedup vs baseline: 4.0250x; 1.0676x over previous
//
#include <hip/hip_runtime.h>
#include <cstddef>
#include <cstdint>

#define N_SRC 100000
#define N_DST 100000
#define NE    1000000
#define D     128
#define R     3
#define NEG   0.2f
#define N3    (R * N_DST)                 // 300000 flattened (r,dst) rows
#define NE3   (R * NE)                    // 3000000 edges
#define NB3   ((N3 + 255) / 256)          // 1172
#define NROWS_SEM (R * N_DST)
#define NBH   ((N_SRC + 127) / 128)       // 782 blocks per relation
#define NBS   ((NROWS_SEM + 127) / 128)   // 2344

typedef __attribute__((ext_vector_type(8))) short bf16x8;
typedef __attribute__((ext_vector_type(4))) float f32x4;

__device__ __forceinline__ float b2f(unsigned short u) {
    union { unsigned int i; float f; } v; v.i = ((unsigned int)u) << 16; return v.f;
}
__device__ __forceinline__ unsigned short f2b(float f) {
    union { float f; unsigned int i; } v; v.f = f;
    unsigned int x = v.i;
    return (unsigned short)((x + 0x7fffu + ((x >> 16) & 1u)) >> 16);  // RNE
}
__device__ __forceinline__ float eluf(float x) {
    return x > 0.f ? x : expm1f(x);
}

// v[r][k] = sum_c W[r][k][c] * attn_r[r][c]
__global__ void compute_v(const float* __restrict__ fcW, const float* __restrict__ attn_r,
                          float* __restrict__ v) {
    int r = blockIdx.x;
    int i = threadIdx.x;
    const float* Wrow = fcW + ((size_t)r * D + i) * D;
    const float* ar = attn_r + r * D;
    float s = 0.f;
    #pragma unroll 4
    for (int j = 0; j < D; j++) s += Wrow[j] * ar[j];
    v[r * D + i] = s;
}

// Whi_t/Wlo_t[r][n][k] = split_bf16(W[r][k][n])
__global__ void prep_w(const float* __restrict__ fcW, unsigned short* __restrict__ Wh,
                       unsigned short* __restrict__ Wl) {
    int r = blockIdx.x;
    for (int i = threadIdx.x; i < D * D; i += 256) {
        int n = i >> 7, k = i & 127;
        float x = fcW[(size_t)r * D * D + k * D + n];
        unsigned short hi = f2b(x);
        Wh[(size_t)r * D * D + i] = hi;
        Wl[(size_t)r * D * D + i] = f2b(x - b2f(hi));
    }
}

__global__ void prep_w1(const float* __restrict__ W1, unsigned short* __restrict__ W1t) {
    for (int i = threadIdx.x; i < D * D; i += 256) {
        int n = i >> 7, k = i & 127;
        W1t[i] = f2b(W1[k * D + n]);
    }
}

// er3[r][n] = dst_feat[n] . v[r]  — single pass over dst_feat for all relations
__global__ __launch_bounds__(256) void er_all(const float* __restrict__ dst_feat,
                                              const float* __restrict__ v,
                                              float* __restrict__ er3) {
    int gw = (blockIdx.x * blockDim.x + threadIdx.x) >> 6;
    int lane = threadIdx.x & 63;
    if (gw >= N_DST) return;
    float2 x = ((const float2*)(dst_feat + (size_t)gw * D))[lane];
    #pragma unroll
    for (int r = 0; r < R; r++) {
        float2 vv = ((const float2*)(v + r * D))[lane];
        float s = x.x * vv.x + x.y * vv.y;
        #pragma unroll
        for (int off = 32; off; off >>= 1) s += __shfl_xor(s, off);
        if (lane == 0) er3[(size_t)r * N_DST + gw] = s;
    }
}

// ---------- MFMA GEMM: H = X @ W (bf16x3), fused el, all relations ----------
__global__ __launch_bounds__(512) void gemm_h_all(const float* __restrict__ src_feat,
        const unsigned short* __restrict__ Wh, const unsigned short* __restrict__ Wl,
        const float* __restrict__ attn_l,
        unsigned short* __restrict__ H3, float* __restrict__ el3) {
    __shared__ short Xh[16384], Xl[16384], Bh[16384], Bl[16384];  // 128 KB
    int tid = threadIdx.x;
    int rb = blockIdx.x / NBH, bb = blockIdx.x % NBH;
    const float* X = src_feat + (size_t)rb * N_SRC * D;
    const unsigned short* WhR = Wh + (size_t)rb * D * D;
    const unsigned short* WlR = Wl + (size_t)rb * D * D;
    const float* al = attn_l + rb * D;
    unsigned short* H = H3 + (size_t)rb * N_SRC * D;
    float* el = el3 + (size_t)rb * N_SRC;
    size_t row0 = (size_t)bb * 128;
    #pragma unroll
    for (int p = 0; p < 8; p++) {
        int c = p * 512 + tid;
        int m = c >> 5, c4 = c & 31;
        float4 xv = make_float4(0.f, 0.f, 0.f, 0.f);
        if (row0 + m < N_SRC) xv = ((const float4*)(X + (row0 + m) * D))[c4];
        unsigned short h0 = f2b(xv.x), h1 = f2b(xv.y), h2 = f2b(xv.z), h3 = f2b(xv.w);
        unsigned short l0 = f2b(xv.x - b2f(h0)), l1 = f2b(xv.y - b2f(h1));
        unsigned short l2 = f2b(xv.z - b2f(h2)), l3 = f2b(xv.w - b2f(h3));
        int idx = m * 128 + (((c4 >> 1) ^ (m & 7)) << 3) + ((c4 & 1) << 2);
        *(uint2*)&Xh[idx] = make_uint2((unsigned)h0 | ((unsigned)h1 << 16),
                                       (unsigned)h2 | ((unsigned)h3 << 16));
        *(uint2*)&Xl[idx] = make_uint2((unsigned)l0 | ((unsigned)l1 << 16),
                                       (unsigned)l2 | ((unsigned)l3 << 16));
    }
    #pragma unroll
    for (int p = 0; p < 4; p++) {
        int c = p * 512 + tid;
        int n = c >> 4, cb = c & 15;
        int idx = n * 128 + ((cb ^ (n & 7)) << 3);
        *(uint4*)&Bh[idx] = ((const uint4*)WhR)[c];
        *(uint4*)&Bl[idx] = ((const uint4*)WlR)[c];
    }
    __syncthreads();

    int w = tid >> 6, lane = tid & 63, lr = lane & 15, lg = lane >> 4;
    f32x4 acc[8];
    #pragma unroll
    for (int nt = 0; nt < 8; nt++) acc[nt] = (f32x4){0.f, 0.f, 0.f, 0.f};
    int m = w * 16 + lr;
    #pragma unroll
    for (int kk = 0; kk < 4; kk++) {
        int cb = kk * 4 + lg;
        int ia = m * 128 + ((cb ^ (m & 7)) << 3);
        bf16x8 ah = *(const bf16x8*)&Xh[ia];
        bf16x8 alo = *(const bf16x8*)&Xl[ia];
        #pragma unroll
        for (int nt = 0; nt < 8; nt++) {
            int n = nt * 16 + lr;
            int ib = n * 128 + ((cb ^ (n & 7)) << 3);
            bf16x8 bh = *(const bf16x8*)&Bh[ib];
            bf16x8 bl = *(const bf16x8*)&Bl[ib];
            acc[nt] = __builtin_amdgcn_mfma_f32_16x16x32_bf16(ah, bh, acc[nt], 0, 0, 0);
            acc[nt] = __builtin_amdgcn_mfma_f32_16x16x32_bf16(alo, bh, acc[nt], 0, 0, 0);
            acc[nt] = __builtin_amdgcn_mfma_f32_16x16x32_bf16(ah, bl, acc[nt], 0, 0, 0);
        }
    }
    float alv[8];
    #pragma unroll
    for (int nt = 0; nt < 8; nt++) alv[nt] = al[nt * 16 + lr];
    #pragma unroll
    for (int reg = 0; reg < 4; reg++) {
        size_t row = row0 + w * 16 + lg * 4 + reg;
        bool ok = row < N_SRC;
        float ep = 0.f;
        #pragma unroll
        for (int nt = 0; nt < 8; nt++) {
            float hv = acc[nt][reg];
            ep = fmaf(hv, alv[nt], ep);
            if (ok) H[row * D + nt * 16 + lr] = f2b(hv);
        }
        ep += __shfl_xor(ep, 1); ep += __shfl_xor(ep, 2);
        ep += __shfl_xor(ep, 4); ep += __shfl_xor(ep, 8);
        if (ok && lr == 0) el[row] = ep;
    }
}

// ---------- MFMA GEMM: semantic partials (z is bf16) ----------
__global__ __launch_bounds__(512) void gemm_sem(const unsigned short* __restrict__ Z,
        const unsigned short* __restrict__ W1t, const float* __restrict__ b1,
        const float* __restrict__ w2, float* __restrict__ psem) {
    __shared__ short Xh[16384], Bh[16384];
    __shared__ float redw[8][4];
    int tid = threadIdx.x;
    size_t row0 = (size_t)blockIdx.x * 128;
    #pragma unroll
    for (int p = 0; p < 4; p++) {
        int c = p * 512 + tid;
        int m = c >> 4, cb = c & 15;
        uint4 xv = make_uint4(0u, 0u, 0u, 0u);
        if (row0 + m < NROWS_SEM) xv = ((const uint4*)(Z + (row0 + m) * D))[cb];
        int idx = m * 128 + ((cb ^ (m & 7)) << 3);
        *(uint4*)&Xh[idx] = xv;
    }
    #pragma unroll
    for (int p = 0; p < 4; p++) {
        int c = p * 512 + tid;
        int n = c >> 4, cb = c & 15;
        int idx = n * 128 + ((cb ^ (n & 7)) << 3);
        *(uint4*)&Bh[idx] = ((const uint4*)W1t)[c];
    }
    __syncthreads();

    int w = tid >> 6, lane = tid & 63, lr = lane & 15, lg = lane >> 4;
    f32x4 acc[8];
    #pragma unroll
    for (int nt = 0; nt < 8; nt++) acc[nt] = (f32x4){0.f, 0.f, 0.f, 0.f};
    int m = w * 16 + lr;
    #pragma unroll
    for (int kk = 0; kk < 4; kk++) {
        int cb = kk * 4 + lg;
        int ia = m * 128 + ((cb ^ (m & 7)) << 3);
        bf16x8 ah = *(const bf16x8*)&Xh[ia];
        #pragma unroll
        for (int nt = 0; nt < 8; nt++) {
            int n = nt * 16 + lr;
            int ib = n * 128 + ((cb ^ (n & 7)) << 3);
            bf16x8 bh = *(const bf16x8*)&Bh[ib];
            acc[nt] = __builtin_amdgcn_mfma_f32_16x16x32_bf16(ah, bh, acc[nt], 0, 0, 0);
        }
    }
    float b1v[8], w2v[8];
    #pragma unroll
    for (int nt = 0; nt < 8; nt++) { b1v[nt] = b1[nt * 16 + lr]; w2v[nt] = w2[nt * 16 + lr]; }
    float rs0 = 0.f, rs1 = 0.f, rs2 = 0.f;
    #pragma unroll
    for (int reg = 0; reg < 4; reg++) {
        size_t row = row0 + w * 16 + lg * 4 + reg;
        float sv = 0.f;
        #pragma unroll
        for (int nt = 0; nt < 8; nt++)
            sv += tanhf(acc[nt][reg] + b1v[nt]) * w2v[nt];
        sv += __shfl_xor(sv, 1); sv += __shfl_xor(sv, 2);
        sv += __shfl_xor(sv, 4); sv += __shfl_xor(sv, 8);
        if (lr == 0 && row < NROWS_SEM) {
            int r = (int)(row / N_DST);
            if (r == 0) rs0 += sv; else if (r == 1) rs1 += sv; else rs2 += sv;
        }
    }
    rs0 += __shfl_xor(rs0, 16); rs0 += __shfl_xor(rs0, 32);
    rs1 += __shfl_xor(rs1, 16); rs1 += __shfl_xor(rs1, 32);
    rs2 += __shfl_xor(rs2, 16); rs2 += __shfl_xor(rs2, 32);
    if (lane == 0) { redw[w][0] = rs0; redw[w][1] = rs1; redw[w][2] = rs2; }
    __syncthreads();
    if (tid < 3) {
        float s = 0.f;
        #pragma unroll
        for (int i = 0; i < 8; i++) s += redw[i][tid];
        psem[blockIdx.x * 3 + tid] = s;
    }
}

// ---------- CSR build over all relations ----------
__global__ void count_all(const int* __restrict__ ed3, int* __restrict__ cnt3) {
    int i = blockIdx.x * blockDim.x + threadIdx.x;
    if (i >= NE3) return;
    int r = i / NE;
    atomicAdd(&cnt3[(size_t)r * N_DST + ed3[i]], 1);
}

__global__ void scan_blocks(int* __restrict__ rowptr, int* __restrict__ bsum) {
    __shared__ int tmp[256];
    int i = blockIdx.x * 256 + threadIdx.x;
    int x = (i < N3) ? rowptr[i] : 0;
    tmp[threadIdx.x] = x;
    __syncthreads();
    #pragma unroll
    for (int off = 1; off < 256; off <<= 1) {
        int v = (threadIdx.x >= off) ? tmp[threadIdx.x - off] : 0;
        __syncthreads();
        tmp[threadIdx.x] += v;
        __syncthreads();
    }
    if (i < N3) rowptr[i] = tmp[threadIdx.x] - x;
    if (threadIdx.x == 255) bsum[blockIdx.x] = tmp[255];
}

// global scan of NB3=1172 block sums: 1 block, 1024 threads, 2 elems/thread
__global__ __launch_bounds__(1024) void scan_bsum(int* __restrict__ bsum) {
    __shared__ int sums[1024];
    int t = threadIdx.x;
    int i0 = 2 * t, i1 = 2 * t + 1;
    int a0 = (i0 < NB3) ? bsum[i0] : 0;
    int a1 = (i1 < NB3) ? bsum[i1] : 0;
    sums[t] = a0 + a1;
    __syncthreads();
    #pragma unroll
    for (int off = 1; off < 1024; off <<= 1) {
        int v = (t >= off) ? sums[t - off] : 0;
        __syncthreads();
        sums[t] += v;
        __syncthreads();
    }
    int base = (t > 0) ? sums[t - 1] : 0;
    if (i0 < NB3) bsum[i0] = base;
    if (i1 < NB3) bsum[i1] = base + a0;
}

__global__ void add_offsets(int* __restrict__ rowptr, const int* __restrict__ bsum,
                            int* __restrict__ cursor) {
    int i = blockIdx.x * 256 + threadIdx.x;
    if (i < N3) {
        int vv = rowptr[i] + bsum[blockIdx.x];
        rowptr[i] = vv;
        cursor[i] = vv;
    }
    if (i == 0) rowptr[N3] = NE3;
}

__global__ void place_all(const int* __restrict__ es3, const int* __restrict__ ed3,
                          int* __restrict__ cursor3, int* __restrict__ csr_src) {
    int i = blockIdx.x * blockDim.x + threadIdx.x;
    if (i >= NE3) return;
    int r = i / NE;
    int pos = atomicAdd(&cursor3[(size_t)r * N_DST + ed3[i]], 1);
    csr_src[pos] = es3[i];
}

// ---------- per-(r,dst) gather + softmax + elu, z stored bf16 ----------
__global__ __launch_bounds__(256) void aggregate_all(const unsigned short* __restrict__ hsrc3,
                                                     const int* __restrict__ csr_src,
                                                     const int* __restrict__ rowptr3,
                                                     const float* __restrict__ el3,
                                                     const float* __restrict__ er3,
                                                     const float* __restrict__ gat_bias,
                                                     unsigned short* __restrict__ z3) {
    int gw3 = (blockIdx.x * blockDim.x + threadIdx.x) >> 6;
    int lane = threadIdx.x & 63;
    if (gw3 >= N3) return;
    int r = gw3 / N_DST;
    int beg = rowptr3[gw3], end = rowptr3[gw3 + 1];
    float erd = er3[gw3];
    const unsigned short* hs = hsrc3 + (size_t)r * N_SRC * D;
    const float* elr = el3 + (size_t)r * N_SRC;
    float2 acc = make_float2(0.f, 0.f);
    float sum = 0.f;
    int i = beg;
    for (; i + 2 <= end; i += 2) {
        int s0 = csr_src[i], s1 = csr_src[i + 1];
        float e0 = elr[s0] + erd, e1 = elr[s1] + erd;
        e0 = e0 > 0.f ? e0 : NEG * e0;
        e1 = e1 > 0.f ? e1 : NEG * e1;
        float x0 = expf(e0), x1 = expf(e1);
        ushort2 u0 = ((const ushort2*)(hs + (size_t)s0 * D))[lane];
        ushort2 u1 = ((const ushort2*)(hs + (size_t)s1 * D))[lane];
        acc.x = fmaf(x0, b2f(u0.x), acc.x);
        acc.y = fmaf(x0, b2f(u0.y), acc.y);
        acc.x = fmaf(x1, b2f(u1.x), acc.x);
        acc.y = fmaf(x1, b2f(u1.y), acc.y);
        sum += x0 + x1;
    }
    if (i < end) {
        int s0 = csr_src[i];
        float e0 = elr[s0] + erd;
        e0 = e0 > 0.f ? e0 : NEG * e0;
        float x0 = expf(e0);
        ushort2 u0 = ((const ushort2*)(hs + (size_t)s0 * D))[lane];
        acc.x = fmaf(x0, b2f(u0.x), acc.x);
        acc.y = fmaf(x0, b2f(u0.y), acc.y);
        sum += x0;
    }
    float inv = sum > 0.f ? 1.f / sum : 0.f;
    float2 b = ((const float2*)(gat_bias + r * D))[lane];
    ushort2 zu;
    zu.x = f2b(eluf(fmaf(acc.x, inv, b.x)));
    zu.y = f2b(eluf(fmaf(acc.y, inv, b.y)));
    ((ushort2*)(z3 + (size_t)gw3 * D))[lane] = zu;
}

__global__ void finalize_a(const float* __restrict__ psem, float* __restrict__ a_ws,
                           float* __restrict__ out_tail) {
    __shared__ float red[4][4];
    float s0 = 0.f, s1 = 0.f, s2 = 0.f;
    for (int b = threadIdx.x; b < NBS; b += 256) {
        s0 += psem[b * 3]; s1 += psem[b * 3 + 1]; s2 += psem[b * 3 + 2];
    }
    #pragma unroll
    for (int off = 32; off; off >>= 1) {
        s0 += __shfl_xor(s0, off); s1 += __shfl_xor(s1, off); s2 += __shfl_xor(s2, off);
    }
    int w = threadIdx.x >> 6;
    if ((threadIdx.x & 63) == 0) { red[w][0] = s0; red[w][1] = s1; red[w][2] = s2; }
    __syncthreads();
    if (threadIdx.x == 0) {
        float w0 = 0.f, w1 = 0.f, w2v = 0.f;
        #pragma unroll
        for (int i = 0; i < 4; i++) { w0 += red[i][0]; w1 += red[i][1]; w2v += red[i][2]; }
        w0 /= (float)N_DST; w1 /= (float)N_DST; w2v /= (float)N_DST;
        float m = fmaxf(w0, fmaxf(w1, w2v));
        float e0 = expf(w0 - m), e1 = expf(w1 - m), e2 = expf(w2v - m);
        float s = e0 + e1 + e2;
        a_ws[0] = e0 / s; a_ws[1] = e1 / s; a_ws[2] = e2 / s;
        out_tail[0] = e0 / s; out_tail[1] = e1 / s; out_tail[2] = e2 / s;
    }
}

// z_out = sum_r a[r] * z[r]  (z bf16, out fp32), 8 elems/thread
__global__ __launch_bounds__(256) void combine(const unsigned short* __restrict__ z3,
                                               const float* __restrict__ a,
                                               float* __restrict__ out) {
    size_t f = (size_t)blockIdx.x * blockDim.x + threadIdx.x;  // uint4 (8 bf16) index
    if (f >= (size_t)N_DST * D / 8) return;
    float accv[8] = {};
    #pragma unroll
    for (int r = 0; r < R; r++) {
        float ar = a[r];
        uint4 u = ((const uint4*)z3)[(size_t)r * (N_DST * D / 8) + f];
        unsigned int uu[4] = {u.x, u.y, u.z, u.w};
        #pragma unroll
        for (int q = 0; q < 4; q++) {
            accv[2 * q]     = fmaf(ar, b2f((unsigned short)(uu[q] & 0xffff)), accv[2 * q]);
            accv[2 * q + 1] = fmaf(ar, b2f((unsigned short)(uu[q] >> 16)), accv[2 * q + 1]);
        }
    }
    float4* o4 = (float4*)(out + f * 8);
    o4[0] = make_float4(accv[0], accv[1], accv[2], accv[3]);
    o4[1] = make_float4(accv[4], accv[5], accv[6], accv[7]);
}

extern "C" void kernel_launch(void* const* d_in, const int* in_sizes, int n_in,
                              void* d_out, int out_size, void* d_ws, size_t ws_size,
                              hipStream_t stream) {
    const float* dst_feat = (const float*)d_in[0];
    const float* src_feat = (const float*)d_in[1];
    const float* fcW      = (const float*)d_in[2];
    const float* attn_l   = (const float*)d_in[3];
    const float* attn_r   = (const float*)d_in[4];
    const float* gat_bias = (const float*)d_in[5];
    const float* sem_W1   = (const float*)d_in[6];
    const float* sem_b1   = (const float*)d_in[7];
    const float* sem_w2   = (const float*)d_in[8];
    const int* edge_src   = (const int*)d_in[9];
    const int* edge_dst   = (const int*)d_in[10];
    float* out = (float*)d_out;

    char* p = (char*)d_ws;
    auto alloc = [&](size_t bytes) {
        p = (char*)(((uintptr_t)p + 255) & ~(uintptr_t)255);
        char* r = p; p += bytes; return (void*)r;
    };
    unsigned short* z3   = (unsigned short*)alloc((size_t)N3 * D * sizeof(short));
    unsigned short* hsrc3= (unsigned short*)alloc((size_t)R * N_SRC * D * sizeof(short));
    float* el3    = (float*)alloc((size_t)R * N_SRC * sizeof(float));
    float* er3    = (float*)alloc((size_t)R * N_DST * sizeof(float));
    float* v      = (float*)alloc(R * D * sizeof(float));
    float* a      = (float*)alloc(R * sizeof(float));
    float* psem   = (float*)alloc((size_t)NBS * 3 * sizeof(float));
    unsigned short* Whi  = (unsigned short*)alloc((size_t)R * D * D * sizeof(short));
    unsigned short* Wlo  = (unsigned short*)alloc((size_t)R * D * D * sizeof(short));
    unsigned short* W1t  = (unsigned short*)alloc((size_t)D * D * sizeof(short));
    int* rowptr3 = (int*)alloc((size_t)(N3 + 1) * sizeof(int));
    int* cursor3 = (int*)alloc((size_t)N3 * sizeof(int));
    int* bsum    = (int*)alloc(2048 * sizeof(int));
    int* csr_src = (int*)alloc((size_t)NE3 * sizeof(int));

    prep_w<<<R, 256, 0, stream>>>(fcW, Whi, Wlo);
    prep_w1<<<1, 256, 0, stream>>>(sem_W1, W1t);
    compute_v<<<R, D, 0, stream>>>(fcW, attn_r, v);

    // CSR build (all relations, single global scan)
    hipMemsetAsync(rowptr3, 0, (size_t)(N3 + 1) * sizeof(int), stream);
    count_all<<<(NE3 + 255) / 256, 256, 0, stream>>>(edge_dst, rowptr3);
    scan_blocks<<<NB3, 256, 0, stream>>>(rowptr3, bsum);
    scan_bsum<<<1, 1024, 0, stream>>>(bsum);
    add_offsets<<<NB3, 256, 0, stream>>>(rowptr3, bsum, cursor3);
    place_all<<<(NE3 + 255) / 256, 256, 0, stream>>>(edge_src, edge_dst, cursor3, csr_src);

    // dense phase (all relations)
    gemm_h_all<<<R * NBH, 512, 0, stream>>>(src_feat, Whi, Wlo, attn_l, hsrc3, el3);
    er_all<<<N_DST / 4, 256, 0, stream>>>(dst_feat, v, er3);

    // gather + softmax + elu -> z (bf16)
    aggregate_all<<<N3 / 4, 256, 0, stream>>>(hsrc3, csr_src, rowptr3, el3, er3,
                                              gat_bias, z3);

    gemm_sem<<<NBS, 512, 0, stream>>>(z3, W1t, sem_b1, sem_w2, psem);
    finalize_a<<<1, 256, 0, stream>>>(psem, a, out + (size_t)N_DST * D);
    combine<<<(N_DST * D / 8 + 255) / 256, 256, 0, stream>>>(z3, a, out);
}

// Round 5
// 731.830 us; speedup vs baseline: 4.5617x; 1.1333x over previous
//
#include <hip/hip_runtime.h>
#include <cstddef>
#include <cstdint>

#define N_SRC 100000
#define N_DST 100000
#define NE    1000000
#define D     128
#define R     3
#define NEG   0.2f
#define N3    (R * N_DST)                 // 300000 flattened (r,dst) rows
#define NE3   (R * NE)                    // 3000000 edges
#define NB3   ((N3 + 255) / 256)          // 1172
#define NROWS_SEM (R * N_DST)
#define NBH   ((N_SRC + 127) / 128)       // 782 blocks per relation
#define NBS   ((NROWS_SEM + 127) / 128)   // 2344
#define NGRP  8                           // dst-range groups (≈ XCDs)
#define GBLK  256                         // blocks per group
#define GRNG  (N3 / NGRP)                 // 37500 rows per group

typedef __attribute__((ext_vector_type(8))) short bf16x8;
typedef __attribute__((ext_vector_type(4))) float f32x4;

__device__ __forceinline__ float b2f(unsigned short u) {
    union { unsigned int i; float f; } v; v.i = ((unsigned int)u) << 16; return v.f;
}
__device__ __forceinline__ unsigned short f2b(float f) {
    union { float f; unsigned int i; } v; v.f = f;
    unsigned int x = v.i;
    return (unsigned short)((x + 0x7fffu + ((x >> 16) & 1u)) >> 16);  // RNE
}
__device__ __forceinline__ float eluf(float x) {
    return x > 0.f ? x : expm1f(x);
}

// v[r][k] = sum_c W[r][k][c] * attn_r[r][c]
__global__ void compute_v(const float* __restrict__ fcW, const float* __restrict__ attn_r,
                          float* __restrict__ v) {
    int r = blockIdx.x;
    int i = threadIdx.x;
    const float* Wrow = fcW + ((size_t)r * D + i) * D;
    const float* ar = attn_r + r * D;
    float s = 0.f;
    #pragma unroll 4
    for (int j = 0; j < D; j++) s += Wrow[j] * ar[j];
    v[r * D + i] = s;
}

// Whi_t/Wlo_t[r][n][k] = split_bf16(W[r][k][n])
__global__ void prep_w(const float* __restrict__ fcW, unsigned short* __restrict__ Wh,
                       unsigned short* __restrict__ Wl) {
    int r = blockIdx.x;
    for (int i = threadIdx.x; i < D * D; i += 256) {
        int n = i >> 7, k = i & 127;
        float x = fcW[(size_t)r * D * D + k * D + n];
        unsigned short hi = f2b(x);
        Wh[(size_t)r * D * D + i] = hi;
        Wl[(size_t)r * D * D + i] = f2b(x - b2f(hi));
    }
}

__global__ void prep_w1(const float* __restrict__ W1, unsigned short* __restrict__ W1t) {
    for (int i = threadIdx.x; i < D * D; i += 256) {
        int n = i >> 7, k = i & 127;
        W1t[i] = f2b(W1[k * D + n]);
    }
}

// er3[r][n] = dst_feat[n] . v[r]  — single pass over dst_feat for all relations
__global__ __launch_bounds__(256) void er_all(const float* __restrict__ dst_feat,
                                              const float* __restrict__ v,
                                              float* __restrict__ er3) {
    int gw = (blockIdx.x * blockDim.x + threadIdx.x) >> 6;
    int lane = threadIdx.x & 63;
    if (gw >= N_DST) return;
    float2 x = ((const float2*)(dst_feat + (size_t)gw * D))[lane];
    #pragma unroll
    for (int r = 0; r < R; r++) {
        float2 vv = ((const float2*)(v + r * D))[lane];
        float s = x.x * vv.x + x.y * vv.y;
        #pragma unroll
        for (int off = 32; off; off >>= 1) s += __shfl_xor(s, off);
        if (lane == 0) er3[(size_t)r * N_DST + gw] = s;
    }
}

// ---------- MFMA GEMM: H = X @ W (bf16x3), fused el, all relations ----------
__global__ __launch_bounds__(512) void gemm_h_all(const float* __restrict__ src_feat,
        const unsigned short* __restrict__ Wh, const unsigned short* __restrict__ Wl,
        const float* __restrict__ attn_l,
        unsigned short* __restrict__ H3, float* __restrict__ el3) {
    __shared__ short Xh[16384], Xl[16384], Bh[16384], Bl[16384];  // 128 KB
    int tid = threadIdx.x;
    int rb = blockIdx.x / NBH, bb = blockIdx.x % NBH;
    const float* X = src_feat + (size_t)rb * N_SRC * D;
    const unsigned short* WhR = Wh + (size_t)rb * D * D;
    const unsigned short* WlR = Wl + (size_t)rb * D * D;
    const float* al = attn_l + rb * D;
    unsigned short* H = H3 + (size_t)rb * N_SRC * D;
    float* el = el3 + (size_t)rb * N_SRC;
    size_t row0 = (size_t)bb * 128;
    #pragma unroll
    for (int p = 0; p < 8; p++) {
        int c = p * 512 + tid;
        int m = c >> 5, c4 = c & 31;
        float4 xv = make_float4(0.f, 0.f, 0.f, 0.f);
        if (row0 + m < N_SRC) xv = ((const float4*)(X + (row0 + m) * D))[c4];
        unsigned short h0 = f2b(xv.x), h1 = f2b(xv.y), h2 = f2b(xv.z), h3 = f2b(xv.w);
        unsigned short l0 = f2b(xv.x - b2f(h0)), l1 = f2b(xv.y - b2f(h1));
        unsigned short l2 = f2b(xv.z - b2f(h2)), l3 = f2b(xv.w - b2f(h3));
        int idx = m * 128 + (((c4 >> 1) ^ (m & 7)) << 3) + ((c4 & 1) << 2);
        *(uint2*)&Xh[idx] = make_uint2((unsigned)h0 | ((unsigned)h1 << 16),
                                       (unsigned)h2 | ((unsigned)h3 << 16));
        *(uint2*)&Xl[idx] = make_uint2((unsigned)l0 | ((unsigned)l1 << 16),
                                       (unsigned)l2 | ((unsigned)l3 << 16));
    }
    #pragma unroll
    for (int p = 0; p < 4; p++) {
        int c = p * 512 + tid;
        int n = c >> 4, cb = c & 15;
        int idx = n * 128 + ((cb ^ (n & 7)) << 3);
        *(uint4*)&Bh[idx] = ((const uint4*)WhR)[c];
        *(uint4*)&Bl[idx] = ((const uint4*)WlR)[c];
    }
    __syncthreads();

    int w = tid >> 6, lane = tid & 63, lr = lane & 15, lg = lane >> 4;
    f32x4 acc[8];
    #pragma unroll
    for (int nt = 0; nt < 8; nt++) acc[nt] = (f32x4){0.f, 0.f, 0.f, 0.f};
    int m = w * 16 + lr;
    #pragma unroll
    for (int kk = 0; kk < 4; kk++) {
        int cb = kk * 4 + lg;
        int ia = m * 128 + ((cb ^ (m & 7)) << 3);
        bf16x8 ah = *(const bf16x8*)&Xh[ia];
        bf16x8 alo = *(const bf16x8*)&Xl[ia];
        #pragma unroll
        for (int nt = 0; nt < 8; nt++) {
            int n = nt * 16 + lr;
            int ib = n * 128 + ((cb ^ (n & 7)) << 3);
            bf16x8 bh = *(const bf16x8*)&Bh[ib];
            bf16x8 bl = *(const bf16x8*)&Bl[ib];
            acc[nt] = __builtin_amdgcn_mfma_f32_16x16x32_bf16(ah, bh, acc[nt], 0, 0, 0);
            acc[nt] = __builtin_amdgcn_mfma_f32_16x16x32_bf16(alo, bh, acc[nt], 0, 0, 0);
            acc[nt] = __builtin_amdgcn_mfma_f32_16x16x32_bf16(ah, bl, acc[nt], 0, 0, 0);
        }
    }
    float alv[8];
    #pragma unroll
    for (int nt = 0; nt < 8; nt++) alv[nt] = al[nt * 16 + lr];
    #pragma unroll
    for (int reg = 0; reg < 4; reg++) {
        size_t row = row0 + w * 16 + lg * 4 + reg;
        bool ok = row < N_SRC;
        float ep = 0.f;
        #pragma unroll
        for (int nt = 0; nt < 8; nt++) {
            float hv = acc[nt][reg];
            ep = fmaf(hv, alv[nt], ep);
            if (ok) H[row * D + nt * 16 + lr] = f2b(hv);
        }
        ep += __shfl_xor(ep, 1); ep += __shfl_xor(ep, 2);
        ep += __shfl_xor(ep, 4); ep += __shfl_xor(ep, 8);
        if (ok && lr == 0) el[row] = ep;
    }
}

// ---------- MFMA GEMM: semantic partials (z is bf16) ----------
__global__ __launch_bounds__(512) void gemm_sem(const unsigned short* __restrict__ Z,
        const unsigned short* __restrict__ W1t, const float* __restrict__ b1,
        const float* __restrict__ w2, float* __restrict__ psem) {
    __shared__ short Xh[16384], Bh[16384];
    __shared__ float redw[8][4];
    int tid = threadIdx.x;
    size_t row0 = (size_t)blockIdx.x * 128;
    #pragma unroll
    for (int p = 0; p < 4; p++) {
        int c = p * 512 + tid;
        int m = c >> 4, cb = c & 15;
        uint4 xv = make_uint4(0u, 0u, 0u, 0u);
        if (row0 + m < NROWS_SEM) xv = ((const uint4*)(Z + (row0 + m) * D))[cb];
        int idx = m * 128 + ((cb ^ (m & 7)) << 3);
        *(uint4*)&Xh[idx] = xv;
    }
    #pragma unroll
    for (int p = 0; p < 4; p++) {
        int c = p * 512 + tid;
        int n = c >> 4, cb = c & 15;
        int idx = n * 128 + ((cb ^ (n & 7)) << 3);
        *(uint4*)&Bh[idx] = ((const uint4*)W1t)[c];
    }
    __syncthreads();

    int w = tid >> 6, lane = tid & 63, lr = lane & 15, lg = lane >> 4;
    f32x4 acc[8];
    #pragma unroll
    for (int nt = 0; nt < 8; nt++) acc[nt] = (f32x4){0.f, 0.f, 0.f, 0.f};
    int m = w * 16 + lr;
    #pragma unroll
    for (int kk = 0; kk < 4; kk++) {
        int cb = kk * 4 + lg;
        int ia = m * 128 + ((cb ^ (m & 7)) << 3);
        bf16x8 ah = *(const bf16x8*)&Xh[ia];
        #pragma unroll
        for (int nt = 0; nt < 8; nt++) {
            int n = nt * 16 + lr;
            int ib = n * 128 + ((cb ^ (n & 7)) << 3);
            bf16x8 bh = *(const bf16x8*)&Bh[ib];
            acc[nt] = __builtin_amdgcn_mfma_f32_16x16x32_bf16(ah, bh, acc[nt], 0, 0, 0);
        }
    }
    float b1v[8], w2v[8];
    #pragma unroll
    for (int nt = 0; nt < 8; nt++) { b1v[nt] = b1[nt * 16 + lr]; w2v[nt] = w2[nt * 16 + lr]; }
    float rs0 = 0.f, rs1 = 0.f, rs2 = 0.f;
    #pragma unroll
    for (int reg = 0; reg < 4; reg++) {
        size_t row = row0 + w * 16 + lg * 4 + reg;
        float sv = 0.f;
        #pragma unroll
        for (int nt = 0; nt < 8; nt++)
            sv += tanhf(acc[nt][reg] + b1v[nt]) * w2v[nt];
        sv += __shfl_xor(sv, 1); sv += __shfl_xor(sv, 2);
        sv += __shfl_xor(sv, 4); sv += __shfl_xor(sv, 8);
        if (lr == 0 && row < NROWS_SEM) {
            int r = (int)(row / N_DST);
            if (r == 0) rs0 += sv; else if (r == 1) rs1 += sv; else rs2 += sv;
        }
    }
    rs0 += __shfl_xor(rs0, 16); rs0 += __shfl_xor(rs0, 32);
    rs1 += __shfl_xor(rs1, 16); rs1 += __shfl_xor(rs1, 32);
    rs2 += __shfl_xor(rs2, 16); rs2 += __shfl_xor(rs2, 32);
    if (lane == 0) { redw[w][0] = rs0; redw[w][1] = rs1; redw[w][2] = rs2; }
    __syncthreads();
    if (tid < 3) {
        float s = 0.f;
        #pragma unroll
        for (int i = 0; i < 8; i++) s += redw[i][tid];
        psem[blockIdx.x * 3 + tid] = s;
    }
}

// ---------- CSR build: XCD-range-filtered count & place ----------
// Group g (= blockIdx.x % NGRP, round-robin -> same XCD) owns flattened rows
// [g*GRNG, (g+1)*GRNG): its counter window (150 KB) and csr window (~1.5 MB)
// stay resident in one XCD's L2, so scattered 4B writes fill 64B lines before
// eviction (round-4 place_all: 210 MB WRITE for 12 MB payload).
__global__ __launch_bounds__(256) void count_f(const int* __restrict__ ed3,
                                               int* __restrict__ cnt3) {
    int g = blockIdx.x & (NGRP - 1);
    int j = blockIdx.x / NGRP;
    int lo = g * GRNG, hi = lo + GRNG;
    for (int i = j * 256 + threadIdx.x; i < NE3; i += GBLK * 256) {
        int r = (i >= NE) + (i >= 2 * NE);
        int id3 = r * N_DST + ed3[i];
        if (id3 >= lo && id3 < hi) atomicAdd(&cnt3[id3], 1);
    }
}

__global__ void scan_blocks(int* __restrict__ rowptr, int* __restrict__ bsum) {
    __shared__ int tmp[256];
    int i = blockIdx.x * 256 + threadIdx.x;
    int x = (i < N3) ? rowptr[i] : 0;
    tmp[threadIdx.x] = x;
    __syncthreads();
    #pragma unroll
    for (int off = 1; off < 256; off <<= 1) {
        int v = (threadIdx.x >= off) ? tmp[threadIdx.x - off] : 0;
        __syncthreads();
        tmp[threadIdx.x] += v;
        __syncthreads();
    }
    if (i < N3) rowptr[i] = tmp[threadIdx.x] - x;
    if (threadIdx.x == 255) bsum[blockIdx.x] = tmp[255];
}

// global scan of NB3=1172 block sums
__global__ __launch_bounds__(1024) void scan_bsum(int* __restrict__ bsum) {
    __shared__ int sums[1024];
    int t = threadIdx.x;
    int i0 = 2 * t, i1 = 2 * t + 1;
    int a0 = (i0 < NB3) ? bsum[i0] : 0;
    int a1 = (i1 < NB3) ? bsum[i1] : 0;
    sums[t] = a0 + a1;
    __syncthreads();
    #pragma unroll
    for (int off = 1; off < 1024; off <<= 1) {
        int v = (t >= off) ? sums[t - off] : 0;
        __syncthreads();
        sums[t] += v;
        __syncthreads();
    }
    int base = (t > 0) ? sums[t - 1] : 0;
    if (i0 < NB3) bsum[i0] = base;
    if (i1 < NB3) bsum[i1] = base + a0;
}

__global__ void add_offsets(int* __restrict__ rowptr, const int* __restrict__ bsum,
                            int* __restrict__ cursor) {
    int i = blockIdx.x * 256 + threadIdx.x;
    if (i < N3) {
        int vv = rowptr[i] + bsum[blockIdx.x];
        rowptr[i] = vv;
        cursor[i] = vv;
    }
    if (i == 0) rowptr[N3] = NE3;
}

__global__ __launch_bounds__(256) void place_f(const int* __restrict__ es3,
                                               const int* __restrict__ ed3,
                                               int* __restrict__ cursor3,
                                               int* __restrict__ csr_src) {
    int g = blockIdx.x & (NGRP - 1);
    int j = blockIdx.x / NGRP;
    int lo = g * GRNG, hi = lo + GRNG;
    for (int i = j * 256 + threadIdx.x; i < NE3; i += GBLK * 256) {
        int r = (i >= NE) + (i >= 2 * NE);
        int id3 = r * N_DST + ed3[i];
        if (id3 >= lo && id3 < hi) {
            int pos = atomicAdd(&cursor3[id3], 1);
            csr_src[pos] = es3[i];
        }
    }
}

// ---------- per-(r,dst) gather + softmax + elu, z stored bf16 ----------
__global__ __launch_bounds__(256) void aggregate_all(const unsigned short* __restrict__ hsrc3,
                                                     const int* __restrict__ csr_src,
                                                     const int* __restrict__ rowptr3,
                                                     const float* __restrict__ el3,
                                                     const float* __restrict__ er3,
                                                     const float* __restrict__ gat_bias,
                                                     unsigned short* __restrict__ z3) {
    int gw3 = (blockIdx.x * blockDim.x + threadIdx.x) >> 6;
    int lane = threadIdx.x & 63;
    if (gw3 >= N3) return;
    int r = gw3 / N_DST;
    int beg = rowptr3[gw3], end = rowptr3[gw3 + 1];
    float erd = er3[gw3];
    const unsigned short* hs = hsrc3 + (size_t)r * N_SRC * D;
    const float* elr = el3 + (size_t)r * N_SRC;
    float2 acc = make_float2(0.f, 0.f);
    float sum = 0.f;
    int i = beg;
    for (; i + 2 <= end; i += 2) {
        int s0 = csr_src[i], s1 = csr_src[i + 1];
        float e0 = elr[s0] + erd, e1 = elr[s1] + erd;
        e0 = e0 > 0.f ? e0 : NEG * e0;
        e1 = e1 > 0.f ? e1 : NEG * e1;
        float x0 = expf(e0), x1 = expf(e1);
        ushort2 u0 = ((const ushort2*)(hs + (size_t)s0 * D))[lane];
        ushort2 u1 = ((const ushort2*)(hs + (size_t)s1 * D))[lane];
        acc.x = fmaf(x0, b2f(u0.x), acc.x);
        acc.y = fmaf(x0, b2f(u0.y), acc.y);
        acc.x = fmaf(x1, b2f(u1.x), acc.x);
        acc.y = fmaf(x1, b2f(u1.y), acc.y);
        sum += x0 + x1;
    }
    if (i < end) {
        int s0 = csr_src[i];
        float e0 = elr[s0] + erd;
        e0 = e0 > 0.f ? e0 : NEG * e0;
        float x0 = expf(e0);
        ushort2 u0 = ((const ushort2*)(hs + (size_t)s0 * D))[lane];
        acc.x = fmaf(x0, b2f(u0.x), acc.x);
        acc.y = fmaf(x0, b2f(u0.y), acc.y);
        sum += x0;
    }
    float inv = sum > 0.f ? 1.f / sum : 0.f;
    float2 b = ((const float2*)(gat_bias + r * D))[lane];
    ushort2 zu;
    zu.x = f2b(eluf(fmaf(acc.x, inv, b.x)));
    zu.y = f2b(eluf(fmaf(acc.y, inv, b.y)));
    ((ushort2*)(z3 + (size_t)gw3 * D))[lane] = zu;
}

__global__ void finalize_a(const float* __restrict__ psem, float* __restrict__ a_ws,
                           float* __restrict__ out_tail) {
    __shared__ float red[4][4];
    float s0 = 0.f, s1 = 0.f, s2 = 0.f;
    for (int b = threadIdx.x; b < NBS; b += 256) {
        s0 += psem[b * 3]; s1 += psem[b * 3 + 1]; s2 += psem[b * 3 + 2];
    }
    #pragma unroll
    for (int off = 32; off; off >>= 1) {
        s0 += __shfl_xor(s0, off); s1 += __shfl_xor(s1, off); s2 += __shfl_xor(s2, off);
    }
    int w = threadIdx.x >> 6;
    if ((threadIdx.x & 63) == 0) { red[w][0] = s0; red[w][1] = s1; red[w][2] = s2; }
    __syncthreads();
    if (threadIdx.x == 0) {
        float w0 = 0.f, w1 = 0.f, w2v = 0.f;
        #pragma unroll
        for (int i = 0; i < 4; i++) { w0 += red[i][0]; w1 += red[i][1]; w2v += red[i][2]; }
        w0 /= (float)N_DST; w1 /= (float)N_DST; w2v /= (float)N_DST;
        float m = fmaxf(w0, fmaxf(w1, w2v));
        float e0 = expf(w0 - m), e1 = expf(w1 - m), e2 = expf(w2v - m);
        float s = e0 + e1 + e2;
        a_ws[0] = e0 / s; a_ws[1] = e1 / s; a_ws[2] = e2 / s;
        out_tail[0] = e0 / s; out_tail[1] = e1 / s; out_tail[2] = e2 / s;
    }
}

// z_out = sum_r a[r] * z[r]  (z bf16, out fp32), 8 elems/thread
__global__ __launch_bounds__(256) void combine(const unsigned short* __restrict__ z3,
                                               const float* __restrict__ a,
                                               float* __restrict__ out) {
    size_t f = (size_t)blockIdx.x * blockDim.x + threadIdx.x;  // uint4 (8 bf16) index
    if (f >= (size_t)N_DST * D / 8) return;
    float accv[8] = {};
    #pragma unroll
    for (int r = 0; r < R; r++) {
        float ar = a[r];
        uint4 u = ((const uint4*)z3)[(size_t)r * (N_DST * D / 8) + f];
        unsigned int uu[4] = {u.x, u.y, u.z, u.w};
        #pragma unroll
        for (int q = 0; q < 4; q++) {
            accv[2 * q]     = fmaf(ar, b2f((unsigned short)(uu[q] & 0xffff)), accv[2 * q]);
            accv[2 * q + 1] = fmaf(ar, b2f((unsigned short)(uu[q] >> 16)), accv[2 * q + 1]);
        }
    }
    float4* o4 = (float4*)(out + f * 8);
    o4[0] = make_float4(accv[0], accv[1], accv[2], accv[3]);
    o4[1] = make_float4(accv[4], accv[5], accv[6], accv[7]);
}

extern "C" void kernel_launch(void* const* d_in, const int* in_sizes, int n_in,
                              void* d_out, int out_size, void* d_ws, size_t ws_size,
                              hipStream_t stream) {
    const float* dst_feat = (const float*)d_in[0];
    const float* src_feat = (const float*)d_in[1];
    const float* fcW      = (const float*)d_in[2];
    const float* attn_l   = (const float*)d_in[3];
    const float* attn_r   = (const float*)d_in[4];
    const float* gat_bias = (const float*)d_in[5];
    const float* sem_W1   = (const float*)d_in[6];
    const float* sem_b1   = (const float*)d_in[7];
    const float* sem_w2   = (const float*)d_in[8];
    const int* edge_src   = (const int*)d_in[9];
    const int* edge_dst   = (const int*)d_in[10];
    float* out = (float*)d_out;

    char* p = (char*)d_ws;
    auto alloc = [&](size_t bytes) {
        p = (char*)(((uintptr_t)p + 255) & ~(uintptr_t)255);
        char* r = p; p += bytes; return (void*)r;
    };
    unsigned short* z3   = (unsigned short*)alloc((size_t)N3 * D * sizeof(short));
    unsigned short* hsrc3= (unsigned short*)alloc((size_t)R * N_SRC * D * sizeof(short));
    float* el3    = (float*)alloc((size_t)R * N_SRC * sizeof(float));
    float* er3    = (float*)alloc((size_t)R * N_DST * sizeof(float));
    float* v      = (float*)alloc(R * D * sizeof(float));
    float* a      = (float*)alloc(R * sizeof(float));
    float* psem   = (float*)alloc((size_t)NBS * 3 * sizeof(float));
    unsigned short* Whi  = (unsigned short*)alloc((size_t)R * D * D * sizeof(short));
    unsigned short* Wlo  = (unsigned short*)alloc((size_t)R * D * D * sizeof(short));
    unsigned short* W1t  = (unsigned short*)alloc((size_t)D * D * sizeof(short));
    int* rowptr3 = (int*)alloc((size_t)(N3 + 1) * sizeof(int));
    int* cursor3 = (int*)alloc((size_t)N3 * sizeof(int));
    int* bsum    = (int*)alloc(2048 * sizeof(int));
    int* csr_src = (int*)alloc((size_t)NE3 * sizeof(int));

    prep_w<<<R, 256, 0, stream>>>(fcW, Whi, Wlo);
    prep_w1<<<1, 256, 0, stream>>>(sem_W1, W1t);
    compute_v<<<R, D, 0, stream>>>(fcW, attn_r, v);

    // CSR build (all relations, XCD-range-filtered count/place)
    hipMemsetAsync(rowptr3, 0, (size_t)(N3 + 1) * sizeof(int), stream);
    count_f<<<NGRP * GBLK, 256, 0, stream>>>(edge_dst, rowptr3);
    scan_blocks<<<NB3, 256, 0, stream>>>(rowptr3, bsum);
    scan_bsum<<<1, 1024, 0, stream>>>(bsum);
    add_offsets<<<NB3, 256, 0, stream>>>(rowptr3, bsum, cursor3);
    place_f<<<NGRP * GBLK, 256, 0, stream>>>(edge_src, edge_dst, cursor3, csr_src);

    // dense phase (all relations)
    gemm_h_all<<<R * NBH, 512, 0, stream>>>(src_feat, Whi, Wlo, attn_l, hsrc3, el3);
    er_all<<<N_DST / 4, 256, 0, stream>>>(dst_feat, v, er3);

    // gather + softmax + elu -> z (bf16)
    aggregate_all<<<N3 / 4, 256, 0, stream>>>(hsrc3, csr_src, rowptr3, el3, er3,
                                              gat_bias, z3);

    gemm_sem<<<NBS, 512, 0, stream>>>(z3, W1t, sem_b1, sem_w2, psem);
    finalize_a<<<1, 256, 0, stream>>>(psem, a, out + (size_t)N_DST * D);
    combine<<<(N_DST * D / 8 + 255) / 256, 256, 0, stream>>>(z3, a, out);
}